// Round 1
// baseline (6130.147 us; speedup 1.0000x reference)
//
#include <hip/hip_runtime.h>
#include <hip/hip_bf16.h>
#include <math.h>

// ---------- helpers ----------
__device__ __forceinline__ float bf2f(unsigned short u) {
    return __uint_as_float(((unsigned int)u) << 16);
}
__device__ __forceinline__ unsigned short f2bf(float f) {
    unsigned int x = __float_as_uint(f);
    return (unsigned short)((x + 0x7fffu + ((x >> 16) & 1u)) >> 16);
}

__device__ __forceinline__ void storeC(float* p, float x0, float x1, float x2, float x3) {
    float4 v; v.x = x0; v.y = x1; v.z = x2; v.w = x3;
    *(float4*)p = v;
}
__device__ __forceinline__ void storeC(unsigned short* p, float x0, float x1, float x2, float x3) {
    ushort4 v; v.x = f2bf(x0); v.y = f2bf(x1); v.z = f2bf(x2); v.w = f2bf(x3);
    *(ushort4*)p = v;
}

// ---------- build fused per-edge-type projection weights ----------
// eff[mat][k][h*32+j] = sum_d Wsrc[ts][k][h*32+d] * aw[e][h][d][j]
// mat = e*2 + which (which: 0=att(k-proj), 1=val(v-proj)); ts = (e==0)?0:1
__global__ __launch_bounds__(256) void build_eff(
    const float* __restrict__ Wk, const float* __restrict__ Wv,
    const float* __restrict__ att_w, const float* __restrict__ val_w,
    float* __restrict__ eff)
{
    int gid = blockIdx.x;          // 0 .. 6*256-1
    int mat = gid >> 8;            // 0..5
    int k = gid & 255;
    int e = mat >> 1, which = mat & 1;
    int ts = (e == 0) ? 0 : 1;
    int c = threadIdx.x;           // 0..255
    int h = c >> 5, j = c & 31;
    const float* Wsrc = (which == 0 ? Wk : Wv) + ((size_t)ts * 256 + k) * 256 + h * 32;
    const float* aw = (which == 0 ? att_w : val_w) + (size_t)((e * 8 + h) * 32) * 32 + j;
    float s = 0.f;
    #pragma unroll
    for (int d = 0; d < 32; ++d) s += Wsrc[d] * aw[d * 32];
    eff[((size_t)mat * 256 + k) * 256 + c] = s;
}

__global__ void build_eff_bias(
    const float* __restrict__ bk, const float* __restrict__ bv,
    const float* __restrict__ att_w, const float* __restrict__ val_w,
    float* __restrict__ effb)
{
    int mat = blockIdx.x;          // 0..5
    int c = threadIdx.x;           // 0..255
    int e = mat >> 1, which = mat & 1;
    int ts = (e == 0) ? 0 : 1;
    int h = c >> 5, j = c & 31;
    const float* bsrc = (which == 0 ? bk : bv) + ts * 256 + h * 32;
    const float* aw = (which == 0 ? att_w : val_w) + (size_t)((e * 8 + h) * 32) * 32 + j;
    float s = 0.f;
    #pragma unroll
    for (int d = 0; d < 32; ++d) s += bsrc[d] * aw[d * 32];
    effb[mat * 256 + c] = s;
}

// ---------- generic GEMM: C[M,256] = A[M,256] @ W[256,256] (+bias) ----------
// 64x64 tile, BK=32, 256 threads, 4x4 micro-tile, transposed-A/B LDS (b128 reads)
template <typename OutT>
__global__ __launch_bounds__(256) void gemm_k256(
    const float* __restrict__ A, const float* __restrict__ W,
    const float* __restrict__ bias, OutT* __restrict__ C, int M)
{
    __shared__ float As[32][72];   // As[k][m]
    __shared__ float Bs[32][72];   // Bs[k][n]
    int t = threadIdx.x;
    int m0 = blockIdx.y * 64, n0 = blockIdx.x * 64;
    int tx = t & 15, ty = t >> 4;
    int arow = t >> 2, akk = (t & 3) * 8;  // A loader: row 0..63, k-chunk of 8
    int brow = t >> 3, bcc = (t & 7) * 8;  // B loader: k-row 0..31, n-chunk of 8
    const float* Aptr = A + (size_t)(m0 + arow) * 256 + akk;
    bool aok = (m0 + arow) < M;
    const float* Wptr = W + (size_t)brow * 256 + n0 + bcc;

    float acc[4][4] = {};
    for (int k0 = 0; k0 < 256; k0 += 32) {
        float4 a0 = {0,0,0,0}, a1 = {0,0,0,0};
        if (aok) {
            a0 = *(const float4*)(Aptr + k0);
            a1 = *(const float4*)(Aptr + k0 + 4);
        }
        float4 b0 = *(const float4*)(Wptr + (size_t)k0 * 256);
        float4 b1 = *(const float4*)(Wptr + (size_t)k0 * 256 + 4);
        __syncthreads();
        As[akk + 0][arow] = a0.x; As[akk + 1][arow] = a0.y;
        As[akk + 2][arow] = a0.z; As[akk + 3][arow] = a0.w;
        As[akk + 4][arow] = a1.x; As[akk + 5][arow] = a1.y;
        As[akk + 6][arow] = a1.z; As[akk + 7][arow] = a1.w;
        *(float4*)&Bs[brow][bcc] = b0;
        *(float4*)&Bs[brow][bcc + 4] = b1;
        __syncthreads();
        #pragma unroll
        for (int k = 0; k < 32; ++k) {
            const float4 av = *(const float4*)&As[k][ty * 4];
            const float4 bv = *(const float4*)&Bs[k][tx * 4];
            float aa[4] = {av.x, av.y, av.z, av.w};
            float bb[4] = {bv.x, bv.y, bv.z, bv.w};
            #pragma unroll
            for (int i = 0; i < 4; ++i)
                #pragma unroll
                for (int j = 0; j < 4; ++j)
                    acc[i][j] += aa[i] * bb[j];
        }
    }

    int cbase = n0 + tx * 4;
    float bv0 = 0, bv1 = 0, bv2 = 0, bv3 = 0;
    if (bias) { bv0 = bias[cbase]; bv1 = bias[cbase+1]; bv2 = bias[cbase+2]; bv3 = bias[cbase+3]; }
    #pragma unroll
    for (int i = 0; i < 4; ++i) {
        int row = m0 + ty * 4 + i;
        if (row < M) {
            storeC(C + (size_t)row * 256 + cbase,
                   acc[i][0] + bv0, acc[i][1] + bv1, acc[i][2] + bv2, acc[i][3] + bv3);
        }
    }
}

// ---------- per-edge attention + aggregation (one wave per edge) ----------
__global__ __launch_bounds__(256) void edge_agg(
    const int* __restrict__ src, const int* __restrict__ dst, int E,
    const unsigned short* __restrict__ q,    // [Nd,256] bf16
    const unsigned short* __restrict__ ke,   // [Ns,256] bf16
    const unsigned short* __restrict__ ve,   // [Ns,256] bf16
    const float* __restrict__ canon,         // [8]
    float rsdk,
    float* __restrict__ agg, float* __restrict__ den)
{
    int wave = threadIdx.x >> 6, lane = threadIdx.x & 63;
    int e = blockIdx.x * 4 + wave;
    if (e >= E) return;
    int s = src[e], d = dst[e];
    ushort4 qv = *(const ushort4*)(q + (size_t)d * 256 + lane * 4);
    ushort4 kv = *(const ushort4*)(ke + (size_t)s * 256 + lane * 4);
    float p = bf2f(qv.x) * bf2f(kv.x) + bf2f(qv.y) * bf2f(kv.y)
            + bf2f(qv.z) * bf2f(kv.z) + bf2f(qv.w) * bf2f(kv.w);
    p += __shfl_xor(p, 1);
    p += __shfl_xor(p, 2);
    p += __shfl_xor(p, 4);
    int h = lane >> 3;
    float ex = __expf(p * canon[h] * rsdk);
    if ((lane & 7) == 0) atomicAdd(&den[(size_t)d * 8 + h], ex);
    ushort4 vv = *(const ushort4*)(ve + (size_t)s * 256 + lane * 4);
    float* ap = agg + (size_t)d * 256 + lane * 4;
    atomicAdd(ap + 0, ex * bf2f(vv.x));
    atomicAdd(ap + 1, ex * bf2f(vv.y));
    atomicAdd(ap + 2, ex * bf2f(vv.z));
    atomicAdd(ap + 3, ex * bf2f(vv.w));
}

// ---------- softmax-normalize aggregates (in place) ----------
__global__ void norm_author(float* __restrict__ agg, const float* __restrict__ den, int N) {
    int i = blockIdx.x * blockDim.x + threadIdx.x;   // per float4
    if (i >= N * 64) return;
    int n = i >> 6, h = (i & 63) >> 3;
    float dv = den[(size_t)n * 8 + h];
    float4* p = (float4*)agg + i;
    float4 v = *p;
    float r = dv > 0.f ? 1.f / dv : 0.f;
    v.x *= r; v.y *= r; v.z *= r; v.w *= r;
    *p = v;
}

__global__ void norm_paper(float* __restrict__ aggw, const float* __restrict__ aggc,
                           const float* __restrict__ denw, const float* __restrict__ denc, int N) {
    int i = blockIdx.x * blockDim.x + threadIdx.x;
    if (i >= N * 64) return;
    int n = i >> 6, h = (i & 63) >> 3;
    float dw = denw[(size_t)n * 8 + h], dc = denc[(size_t)n * 8 + h];
    float rw = dw > 0.f ? 0.5f / dw : 0.f;
    float rc = dc > 0.f ? 0.5f / dc : 0.f;
    float4 vw = ((float4*)aggw)[i];
    float4 vc = ((const float4*)aggc)[i];
    float4 o;
    o.x = vw.x * rw + vc.x * rc;
    o.y = vw.y * rw + vc.y * rc;
    o.z = vw.z * rw + vc.z * rc;
    o.w = vw.w * rw + vc.w * rc;
    ((float4*)aggw)[i] = o;
}

// ---------- residual gate + LayerNorm (one wave per row) ----------
__global__ __launch_bounds__(256) void finalize_ln(
    const float* __restrict__ pre,   // [N,256] = t @ Wfc
    const float* __restrict__ hin,   // [N,256]
    const float* __restrict__ bfc, const float* __restrict__ g,
    const float* __restrict__ b, const float* __restrict__ res, int nid,
    float* __restrict__ out, int N)
{
    int wave = threadIdx.x >> 6, lane = threadIdx.x & 63;
    int row = blockIdx.x * 4 + wave;
    if (row >= N) return;
    float alpha = 1.f / (1.f + __expf(-res[nid]));
    float beta = 1.f - alpha;
    float4 pv = ((const float4*)(pre + (size_t)row * 256))[lane];
    float4 hv = ((const float4*)(hin + (size_t)row * 256))[lane];
    float4 bv = ((const float4*)bfc)[lane];
    float hp0 = (pv.x + bv.x) * alpha + hv.x * beta;
    float hp1 = (pv.y + bv.y) * alpha + hv.y * beta;
    float hp2 = (pv.z + bv.z) * alpha + hv.z * beta;
    float hp3 = (pv.w + bv.w) * alpha + hv.w * beta;
    float s = hp0 + hp1 + hp2 + hp3;
    float s2 = hp0 * hp0 + hp1 * hp1 + hp2 * hp2 + hp3 * hp3;
    #pragma unroll
    for (int off = 1; off < 64; off <<= 1) {
        s  += __shfl_xor(s, off);
        s2 += __shfl_xor(s2, off);
    }
    float mu = s * (1.f / 256.f);
    float var = s2 * (1.f / 256.f) - mu * mu;
    float rstd = rsqrtf(var + 1e-5f);
    float4 gv = ((const float4*)g)[lane];
    float4 bbv = ((const float4*)b)[lane];
    float4 o;
    o.x = (hp0 - mu) * rstd * gv.x + bbv.x;
    o.y = (hp1 - mu) * rstd * gv.y + bbv.y;
    o.z = (hp2 - mu) * rstd * gv.z + bbv.z;
    o.w = (hp3 - mu) * rstd * gv.w + bbv.w;
    ((float4*)(out + (size_t)row * 256))[lane] = o;
}

// ---------- launch ----------
extern "C" void kernel_launch(void* const* d_in, const int* in_sizes, int n_in,
                              void* d_out, int out_size, void* d_ws, size_t ws_size,
                              hipStream_t stream)
{
    const float* h_a   = (const float*)d_in[0];
    const float* h_p   = (const float*)d_in[1];
    const int* w_src   = (const int*)d_in[2];
    const int* w_dst   = (const int*)d_in[3];
    const int* wb_src  = (const int*)d_in[4];
    const int* wb_dst  = (const int*)d_in[5];
    const int* c_src   = (const int*)d_in[6];
    const int* c_dst   = (const int*)d_in[7];
    const float* Wk    = (const float*)d_in[8];
    const float* bk    = (const float*)d_in[9];
    const float* Wq    = (const float*)d_in[10];
    const float* bq    = (const float*)d_in[11];
    const float* Wv    = (const float*)d_in[12];
    const float* bv    = (const float*)d_in[13];
    const float* Wfc   = (const float*)d_in[14];
    const float* bfc   = (const float*)d_in[15];
    const float* ln_g  = (const float*)d_in[16];
    const float* ln_b  = (const float*)d_in[17];
    const float* att_w = (const float*)d_in[18];
    const float* val_w = (const float*)d_in[19];
    const float* canon = (const float*)d_in[20];
    const float* res   = (const float*)d_in[21];

    const int NA = in_sizes[0] / 256;
    const int NP = in_sizes[1] / 256;
    const int E0 = in_sizes[2];
    const int E1 = in_sizes[4];
    const int E2 = in_sizes[6];
    const int Nmax = NA > NP ? NA : NP;

    // workspace layout
    char* p = (char*)d_ws;
    auto alloc = [&](size_t bytes) -> char* {
        char* r = p;
        p += (bytes + 255) & ~(size_t)255;
        return r;
    };
    float* eff_w = (float*)alloc((size_t)6 * 65536 * 4);
    float* eff_b = (float*)alloc(6 * 256 * 4);
    unsigned short* qa  = (unsigned short*)alloc((size_t)NA * 256 * 2);
    unsigned short* qp  = (unsigned short*)alloc((size_t)NP * 256 * 2);
    unsigned short* keb = (unsigned short*)alloc((size_t)Nmax * 256 * 2);
    unsigned short* veb = (unsigned short*)alloc((size_t)Nmax * 256 * 2);
    char* agg_start = p;
    float* agg_w  = (float*)alloc((size_t)NP * 256 * 4);
    float* agg_wb = (float*)alloc((size_t)NA * 256 * 4);
    float* agg_c  = (float*)alloc((size_t)NP * 256 * 4);
    float* den_w  = (float*)alloc((size_t)NP * 8 * 4);
    float* den_wb = (float*)alloc((size_t)NA * 8 * 4);
    float* den_c  = (float*)alloc((size_t)NP * 8 * 4);
    size_t agg_bytes = (size_t)(p - agg_start);

    const float rsdk = 0.17677669529663687f;  // 1/sqrt(32)

    // fused weights + zero accumulators
    build_eff<<<dim3(6 * 256), 256, 0, stream>>>(Wk, Wv, att_w, val_w, eff_w);
    build_eff_bias<<<6, 256, 0, stream>>>(bk, bv, att_w, val_w, eff_b);
    hipMemsetAsync(agg_start, 0, agg_bytes, stream);

    dim3 gA(4, (NA + 63) / 64), gP(4, (NP + 63) / 64);

    // q projections
    gemm_k256<unsigned short><<<gA, 256, 0, stream>>>(h_a, Wq,          bq,        qa, NA);
    gemm_k256<unsigned short><<<gP, 256, 0, stream>>>(h_p, Wq + 65536,  bq + 256,  qp, NP);

    // etype 0: writes (author -> paper), q = q_p
    gemm_k256<unsigned short><<<gA, 256, 0, stream>>>(h_a, eff_w,             eff_b,       keb, NA);
    gemm_k256<unsigned short><<<gA, 256, 0, stream>>>(h_a, eff_w + 65536,     eff_b + 256, veb, NA);
    edge_agg<<<(E0 + 3) / 4, 256, 0, stream>>>(w_src, w_dst, E0, qp, keb, veb, canon, rsdk, agg_w, den_w);

    // etype 1: written-by (paper -> author), q = q_a
    gemm_k256<unsigned short><<<gP, 256, 0, stream>>>(h_p, eff_w + 2 * 65536, eff_b + 512, keb, NP);
    gemm_k256<unsigned short><<<gP, 256, 0, stream>>>(h_p, eff_w + 3 * 65536, eff_b + 768, veb, NP);
    edge_agg<<<(E1 + 3) / 4, 256, 0, stream>>>(wb_src, wb_dst, E1, qa, keb, veb, canon + 8, rsdk, agg_wb, den_wb);

    // etype 2: cites (paper -> paper), q = q_p
    gemm_k256<unsigned short><<<gP, 256, 0, stream>>>(h_p, eff_w + 4 * 65536, eff_b + 1024, keb, NP);
    gemm_k256<unsigned short><<<gP, 256, 0, stream>>>(h_p, eff_w + 5 * 65536, eff_b + 1280, veb, NP);
    edge_agg<<<(E2 + 3) / 4, 256, 0, stream>>>(c_src, c_dst, E2, qp, keb, veb, canon + 16, rsdk, agg_c, den_c);

    // normalize (in place): t_author in agg_wb, t_paper in agg_w
    norm_author<<<(NA * 64 + 255) / 256, 256, 0, stream>>>(agg_wb, den_wb, NA);
    norm_paper<<<(NP * 64 + 255) / 256, 256, 0, stream>>>(agg_w, agg_c, den_w, den_c, NP);

    // output GEMMs; alias freed bf16 buffers as f32 scratch
    float* pre_a = (float*)keb;  // spans keb+veb: 2*Nmax*256*2 >= NA*256*4 bytes
    float* pre_p = (float*)qa;   // spans qa+qp:   (NA+NP)*256*2 >= NP*256*4 bytes
    gemm_k256<float><<<gA, 256, 0, stream>>>(agg_wb, Wfc,         nullptr, pre_a, NA);
    gemm_k256<float><<<gP, 256, 0, stream>>>(agg_w,  Wfc + 65536, nullptr, pre_p, NP);

    // residual gate + LayerNorm
    finalize_ln<<<(NA + 3) / 4, 256, 0, stream>>>(pre_a, h_a, bfc, ln_g, ln_b, res, 0,
                                                  (float*)d_out, NA);
    finalize_ln<<<(NP + 3) / 4, 256, 0, stream>>>(pre_p, h_p, bfc + 256, ln_g + 256, ln_b + 256, res, 1,
                                                  (float*)d_out + (size_t)NA * 256, NP);
}

// Round 3
// 2399.730 us; speedup vs baseline: 2.5545x; 2.5545x over previous
//
#include <hip/hip_runtime.h>
#include <hip/hip_bf16.h>
#include <math.h>

// ---------- helpers ----------
__device__ __forceinline__ float bf2f(unsigned short u) {
    return __uint_as_float(((unsigned int)u) << 16);
}
__device__ __forceinline__ unsigned short f2bf(float f) {
    unsigned int x = __float_as_uint(f);
    return (unsigned short)((x + 0x7fffu + ((x >> 16) & 1u)) >> 16);
}

__device__ __forceinline__ void storeC(float* p, float x0, float x1, float x2, float x3) {
    float4 v; v.x = x0; v.y = x1; v.z = x2; v.w = x3;
    *(float4*)p = v;
}
__device__ __forceinline__ void storeC(unsigned short* p, float x0, float x1, float x2, float x3) {
    ushort4 v; v.x = f2bf(x0); v.y = f2bf(x1); v.z = f2bf(x2); v.w = f2bf(x3);
    *(ushort4*)p = v;
}

// ---------- build fused per-edge-type projection weights ----------
__global__ __launch_bounds__(256) void build_eff(
    const float* __restrict__ Wk, const float* __restrict__ Wv,
    const float* __restrict__ att_w, const float* __restrict__ val_w,
    float* __restrict__ eff)
{
    int gid = blockIdx.x;          // 0 .. 6*256-1
    int mat = gid >> 8;            // 0..5
    int k = gid & 255;
    int e = mat >> 1, which = mat & 1;
    int ts = (e == 0) ? 0 : 1;
    int c = threadIdx.x;           // 0..255
    int h = c >> 5, j = c & 31;
    const float* Wsrc = (which == 0 ? Wk : Wv) + ((size_t)ts * 256 + k) * 256 + h * 32;
    const float* aw = (which == 0 ? att_w : val_w) + (size_t)((e * 8 + h) * 32) * 32 + j;
    float s = 0.f;
    #pragma unroll
    for (int d = 0; d < 32; ++d) s += Wsrc[d] * aw[d * 32];
    eff[((size_t)mat * 256 + k) * 256 + c] = s;
}

__global__ void build_eff_bias(
    const float* __restrict__ bk, const float* __restrict__ bv,
    const float* __restrict__ att_w, const float* __restrict__ val_w,
    float* __restrict__ effb)
{
    int mat = blockIdx.x;          // 0..5
    int c = threadIdx.x;           // 0..255
    int e = mat >> 1, which = mat & 1;
    int ts = (e == 0) ? 0 : 1;
    int h = c >> 5, j = c & 31;
    const float* bsrc = (which == 0 ? bk : bv) + ts * 256 + h * 32;
    const float* aw = (which == 0 ? att_w : val_w) + (size_t)((e * 8 + h) * 32) * 32 + j;
    float s = 0.f;
    #pragma unroll
    for (int d = 0; d < 32; ++d) s += bsrc[d] * aw[d * 32];
    effb[mat * 256 + c] = s;
}

// ---------- generic GEMM: C[M,256] = A[M,256] @ W[256,256] (+bias) ----------
template <typename OutT>
__global__ __launch_bounds__(256) void gemm_k256(
    const float* __restrict__ A, const float* __restrict__ W,
    const float* __restrict__ bias, OutT* __restrict__ C, int M)
{
    __shared__ float As[32][72];   // As[k][m]
    __shared__ float Bs[32][72];   // Bs[k][n]
    int t = threadIdx.x;
    int m0 = blockIdx.y * 64, n0 = blockIdx.x * 64;
    int tx = t & 15, ty = t >> 4;
    int arow = t >> 2, akk = (t & 3) * 8;
    int brow = t >> 3, bcc = (t & 7) * 8;
    const float* Aptr = A + (size_t)(m0 + arow) * 256 + akk;
    bool aok = (m0 + arow) < M;
    const float* Wptr = W + (size_t)brow * 256 + n0 + bcc;

    float acc[4][4] = {};
    for (int k0 = 0; k0 < 256; k0 += 32) {
        float4 a0 = {0,0,0,0}, a1 = {0,0,0,0};
        if (aok) {
            a0 = *(const float4*)(Aptr + k0);
            a1 = *(const float4*)(Aptr + k0 + 4);
        }
        float4 b0 = *(const float4*)(Wptr + (size_t)k0 * 256);
        float4 b1 = *(const float4*)(Wptr + (size_t)k0 * 256 + 4);
        __syncthreads();
        As[akk + 0][arow] = a0.x; As[akk + 1][arow] = a0.y;
        As[akk + 2][arow] = a0.z; As[akk + 3][arow] = a0.w;
        As[akk + 4][arow] = a1.x; As[akk + 5][arow] = a1.y;
        As[akk + 6][arow] = a1.z; As[akk + 7][arow] = a1.w;
        *(float4*)&Bs[brow][bcc] = b0;
        *(float4*)&Bs[brow][bcc + 4] = b1;
        __syncthreads();
        #pragma unroll
        for (int k = 0; k < 32; ++k) {
            const float4 av = *(const float4*)&As[k][ty * 4];
            const float4 bv = *(const float4*)&Bs[k][tx * 4];
            float aa[4] = {av.x, av.y, av.z, av.w};
            float bb[4] = {bv.x, bv.y, bv.z, bv.w};
            #pragma unroll
            for (int i = 0; i < 4; ++i)
                #pragma unroll
                for (int j = 0; j < 4; ++j)
                    acc[i][j] += aa[i] * bb[j];
        }
    }

    int cbase = n0 + tx * 4;
    float bv0 = 0, bv1 = 0, bv2 = 0, bv3 = 0;
    if (bias) { bv0 = bias[cbase]; bv1 = bias[cbase+1]; bv2 = bias[cbase+2]; bv3 = bias[cbase+3]; }
    #pragma unroll
    for (int i = 0; i < 4; ++i) {
        int row = m0 + ty * 4 + i;
        if (row < M) {
            storeC(C + (size_t)row * 256 + cbase,
                   acc[i][0] + bv0, acc[i][1] + bv1, acc[i][2] + bv2, acc[i][3] + bv3);
        }
    }
}

// ---------- CSR build: histogram + scan + scatter ----------
__global__ void k_hist(const int* __restrict__ dst, int E, int* __restrict__ cnt) {
    int e = blockIdx.x * 256 + threadIdx.x;
    if (e < E) atomicAdd(&cnt[dst[e]], 1);
}

__global__ __launch_bounds__(256) void k_scan1(
    const int* __restrict__ cnt, int* __restrict__ offs, int* __restrict__ blksum, int N)
{
    __shared__ int sm[256];
    int t = threadIdx.x, i = blockIdx.x * 256 + t;
    int x = (i < N) ? cnt[i] : 0;
    sm[t] = x; __syncthreads();
    int v = x;
    #pragma unroll
    for (int off = 1; off < 256; off <<= 1) {
        int y = (t >= off) ? sm[t - off] : 0;
        __syncthreads();
        v += y; sm[t] = v;
        __syncthreads();
    }
    if (i < N) offs[i] = v - x;          // exclusive within block
    if (t == 255) blksum[blockIdx.x] = v; // block total
}

__global__ __launch_bounds__(512) void k_scan2(int* __restrict__ blksum, int nb) {
    __shared__ int sm[512];
    int t = threadIdx.x;
    int x = (t < nb) ? blksum[t] : 0;
    sm[t] = x; __syncthreads();
    int v = x;
    #pragma unroll
    for (int off = 1; off < 512; off <<= 1) {
        int y = (t >= off) ? sm[t - off] : 0;
        __syncthreads();
        v += y; sm[t] = v;
        __syncthreads();
    }
    if (t < nb) blksum[t] = v - x;       // exclusive block offsets, in place
}

__global__ void k_scan3(int* __restrict__ offs, int* __restrict__ cursor,
                        const int* __restrict__ blksum, int N)
{
    int i = blockIdx.x * 256 + threadIdx.x;
    if (i < N) {
        int v = offs[i] + blksum[i >> 8];
        offs[i] = v;
        cursor[i] = v;
    }
}

__global__ void k_scatter(const int* __restrict__ src, const int* __restrict__ dst, int E,
                          int* __restrict__ cursor, int* __restrict__ ssrc)
{
    int e = blockIdx.x * 256 + threadIdx.x;
    if (e < E) {
        int pos = atomicAdd(&cursor[dst[e]], 1);
        ssrc[pos] = src[e];
    }
}

// ---------- CSR aggregation: one wave per destination node ----------
// Computes softmax-normalized sum of ve over incident edges; if `other` is
// given, writes 0.5*(mine + other) (cross-etype mean), else writes mine.
__global__ __launch_bounds__(256) void csr_agg(
    const int* __restrict__ offs, const int* __restrict__ cnt,
    const int* __restrict__ ssrc,
    const unsigned short* __restrict__ q,    // [Nd,256] bf16
    const unsigned short* __restrict__ ke,   // [Ns,256] bf16
    const unsigned short* __restrict__ ve,   // [Ns,256] bf16
    const float* __restrict__ canon,         // [8]
    float rsdk,
    const float* __restrict__ other,
    float* __restrict__ out, int N)
{
    int wave = threadIdx.x >> 6, lane = threadIdx.x & 63;
    int n = blockIdx.x * 4 + wave;
    if (n >= N) return;
    ushort4 qv = *(const ushort4*)(q + (size_t)n * 256 + lane * 4);
    float q0 = bf2f(qv.x), q1 = bf2f(qv.y), q2 = bf2f(qv.z), q3 = bf2f(qv.w);
    int base = offs[n], deg = cnt[n];
    int h = lane >> 3;
    float cw = canon[h] * rsdk;
    float den = 0.f, a0 = 0.f, a1 = 0.f, a2 = 0.f, a3 = 0.f;
    for (int i = 0; i < deg; ++i) {
        int s = ssrc[base + i];
        ushort4 kv = *(const ushort4*)(ke + (size_t)s * 256 + lane * 4);
        float p = q0 * bf2f(kv.x) + q1 * bf2f(kv.y) + q2 * bf2f(kv.z) + q3 * bf2f(kv.w);
        p += __shfl_xor(p, 1);
        p += __shfl_xor(p, 2);
        p += __shfl_xor(p, 4);
        float ex = __expf(p * cw);
        ushort4 vv = *(const ushort4*)(ve + (size_t)s * 256 + lane * 4);
        den += ex;
        a0 += ex * bf2f(vv.x);
        a1 += ex * bf2f(vv.y);
        a2 += ex * bf2f(vv.z);
        a3 += ex * bf2f(vv.w);
    }
    float r = den > 0.f ? 1.f / den : 0.f;
    a0 *= r; a1 *= r; a2 *= r; a3 *= r;
    float4 o;
    if (other) {
        float4 ov = ((const float4*)(other + (size_t)n * 256))[lane];
        o.x = 0.5f * (a0 + ov.x); o.y = 0.5f * (a1 + ov.y);
        o.z = 0.5f * (a2 + ov.z); o.w = 0.5f * (a3 + ov.w);
    } else {
        o.x = a0; o.y = a1; o.z = a2; o.w = a3;
    }
    ((float4*)(out + (size_t)n * 256))[lane] = o;
}

// ---------- residual gate + LayerNorm (one wave per row) ----------
__global__ __launch_bounds__(256) void finalize_ln(
    const float* __restrict__ pre,   // [N,256] = t @ Wfc
    const float* __restrict__ hin,   // [N,256]
    const float* __restrict__ bfc, const float* __restrict__ g,
    const float* __restrict__ b, const float* __restrict__ res, int nid,
    float* __restrict__ out, int N)
{
    int wave = threadIdx.x >> 6, lane = threadIdx.x & 63;
    int row = blockIdx.x * 4 + wave;
    if (row >= N) return;
    float alpha = 1.f / (1.f + __expf(-res[nid]));
    float beta = 1.f - alpha;
    float4 pv = ((const float4*)(pre + (size_t)row * 256))[lane];
    float4 hv = ((const float4*)(hin + (size_t)row * 256))[lane];
    float4 bv = ((const float4*)bfc)[lane];
    float hp0 = (pv.x + bv.x) * alpha + hv.x * beta;
    float hp1 = (pv.y + bv.y) * alpha + hv.y * beta;
    float hp2 = (pv.z + bv.z) * alpha + hv.z * beta;
    float hp3 = (pv.w + bv.w) * alpha + hv.w * beta;
    float s = hp0 + hp1 + hp2 + hp3;
    float s2 = hp0 * hp0 + hp1 * hp1 + hp2 * hp2 + hp3 * hp3;
    #pragma unroll
    for (int off = 1; off < 64; off <<= 1) {
        s  += __shfl_xor(s, off);
        s2 += __shfl_xor(s2, off);
    }
    float mu = s * (1.f / 256.f);
    float var = s2 * (1.f / 256.f) - mu * mu;
    float rstd = rsqrtf(var + 1e-5f);
    float4 gv = ((const float4*)g)[lane];
    float4 bbv = ((const float4*)b)[lane];
    float4 o;
    o.x = (hp0 - mu) * rstd * gv.x + bbv.x;
    o.y = (hp1 - mu) * rstd * gv.y + bbv.y;
    o.z = (hp2 - mu) * rstd * gv.z + bbv.z;
    o.w = (hp3 - mu) * rstd * gv.w + bbv.w;
    ((float4*)(out + (size_t)row * 256))[lane] = o;
}

// ---------- launch ----------
extern "C" void kernel_launch(void* const* d_in, const int* in_sizes, int n_in,
                              void* d_out, int out_size, void* d_ws, size_t ws_size,
                              hipStream_t stream)
{
    const float* h_a   = (const float*)d_in[0];
    const float* h_p   = (const float*)d_in[1];
    const int* w_src   = (const int*)d_in[2];
    const int* w_dst   = (const int*)d_in[3];
    const int* wb_src  = (const int*)d_in[4];
    const int* wb_dst  = (const int*)d_in[5];
    const int* c_src   = (const int*)d_in[6];
    const int* c_dst   = (const int*)d_in[7];
    const float* Wk    = (const float*)d_in[8];
    const float* bk    = (const float*)d_in[9];
    const float* Wq    = (const float*)d_in[10];
    const float* bq    = (const float*)d_in[11];
    const float* Wv    = (const float*)d_in[12];
    const float* bv    = (const float*)d_in[13];
    const float* Wfc   = (const float*)d_in[14];
    const float* bfc   = (const float*)d_in[15];
    const float* ln_g  = (const float*)d_in[16];
    const float* ln_b  = (const float*)d_in[17];
    const float* att_w = (const float*)d_in[18];
    const float* val_w = (const float*)d_in[19];
    const float* canon = (const float*)d_in[20];
    const float* res   = (const float*)d_in[21];

    const int NA = in_sizes[0] / 256;
    const int NP = in_sizes[1] / 256;
    const int E0 = in_sizes[2];
    const int E1 = in_sizes[4];
    const int E2 = in_sizes[6];
    const int Nmax = NA > NP ? NA : NP;
    int Emax = E0 > E1 ? E0 : E1; if (E2 > Emax) Emax = E2;

    // workspace layout
    char* p = (char*)d_ws;
    auto alloc = [&](size_t bytes) -> char* {
        char* r = p;
        p += (bytes + 255) & ~(size_t)255;
        return r;
    };
    float* eff_w = (float*)alloc((size_t)6 * 65536 * 4);
    float* eff_b = (float*)alloc(6 * 256 * 4);
    unsigned short* qa  = (unsigned short*)alloc((size_t)NA * 256 * 2);
    unsigned short* qp  = (unsigned short*)alloc((size_t)NP * 256 * 2);
    unsigned short* keb = (unsigned short*)alloc((size_t)Nmax * 256 * 2);
    unsigned short* veb = (unsigned short*)alloc((size_t)Nmax * 256 * 2);
    float* agg_w  = (float*)alloc((size_t)NP * 256 * 4);   // t_paper accum
    float* agg_wb = (float*)alloc((size_t)NA * 256 * 4);   // t_author
    int* cnt    = (int*)alloc((size_t)Nmax * 4);
    int* offs   = (int*)alloc((size_t)Nmax * 4);
    int* cursor = (int*)alloc((size_t)Nmax * 4);
    int* blksum = (int*)alloc(512 * 4);
    int* ssrc   = (int*)alloc((size_t)Emax * 4);

    const float rsdk = 0.17677669529663687f;  // 1/sqrt(32)

    build_eff<<<dim3(6 * 256), 256, 0, stream>>>(Wk, Wv, att_w, val_w, eff_w);
    build_eff_bias<<<6, 256, 0, stream>>>(bk, bv, att_w, val_w, eff_b);

    dim3 gA(4, (NA + 63) / 64), gP(4, (NP + 63) / 64);

    // q projections
    gemm_k256<unsigned short><<<gA, 256, 0, stream>>>(h_a, Wq,          bq,        qa, NA);
    gemm_k256<unsigned short><<<gP, 256, 0, stream>>>(h_p, Wq + 65536,  bq + 256,  qp, NP);

    auto run_etype = [&](const int* esrc, const int* edst, int E, int Nd,
                         const unsigned short* qn, const float* canon_e,
                         const float* other, float* out) {
        hipMemsetAsync(cnt, 0, (size_t)Nd * 4, stream);
        int gE = (E + 255) / 256, gN = (Nd + 255) / 256;
        k_hist<<<gE, 256, 0, stream>>>(edst, E, cnt);
        k_scan1<<<gN, 256, 0, stream>>>(cnt, offs, blksum, Nd);
        k_scan2<<<1, 512, 0, stream>>>(blksum, gN);
        k_scan3<<<gN, 256, 0, stream>>>(offs, cursor, blksum, Nd);
        k_scatter<<<gE, 256, 0, stream>>>(esrc, edst, E, cursor, ssrc);
        csr_agg<<<(Nd + 3) / 4, 256, 0, stream>>>(offs, cnt, ssrc, qn, keb, veb,
                                                  canon_e, rsdk, other, out, Nd);
    };

    // etype 0: writes (author -> paper), q = q_p
    gemm_k256<unsigned short><<<gA, 256, 0, stream>>>(h_a, eff_w,         eff_b,       keb, NA);
    gemm_k256<unsigned short><<<gA, 256, 0, stream>>>(h_a, eff_w + 65536, eff_b + 256, veb, NA);
    run_etype(w_src, w_dst, E0, NP, qp, canon, nullptr, agg_w);

    // etype 1: written-by (paper -> author), q = q_a
    gemm_k256<unsigned short><<<gP, 256, 0, stream>>>(h_p, eff_w + 2 * 65536, eff_b + 512, keb, NP);
    gemm_k256<unsigned short><<<gP, 256, 0, stream>>>(h_p, eff_w + 3 * 65536, eff_b + 768, veb, NP);
    run_etype(wb_src, wb_dst, E1, NA, qa, canon + 8, nullptr, agg_wb);

    // etype 2: cites (paper -> paper), q = q_p; fuse cross-etype mean with etype0
    gemm_k256<unsigned short><<<gP, 256, 0, stream>>>(h_p, eff_w + 4 * 65536, eff_b + 1024, keb, NP);
    gemm_k256<unsigned short><<<gP, 256, 0, stream>>>(h_p, eff_w + 5 * 65536, eff_b + 1280, veb, NP);
    run_etype(c_src, c_dst, E2, NP, qp, canon + 16, agg_w, agg_w);

    // output GEMMs; alias freed bf16 buffers as f32 scratch
    float* pre_a = (float*)keb;  // keb+veb: 2*Nmax*256*2 bytes >= NA*256*4
    float* pre_p = (float*)qa;   // qa+qp:   (NA+NP)*256*2 bytes >= NP*256*4
    gemm_k256<float><<<gA, 256, 0, stream>>>(agg_wb, Wfc,         nullptr, pre_a, NA);
    gemm_k256<float><<<gP, 256, 0, stream>>>(agg_w,  Wfc + 65536, nullptr, pre_p, NP);

    // residual gate + LayerNorm
    finalize_ln<<<(NA + 3) / 4, 256, 0, stream>>>(pre_a, h_a, bfc, ln_g, ln_b, res, 0,
                                                  (float*)d_out, NA);
    finalize_ln<<<(NP + 3) / 4, 256, 0, stream>>>(pre_p, h_p, bfc + 256, ln_g + 256, ln_b + 256, res, 1,
                                                  (float*)d_out + (size_t)NA * 256, NP);
}

// Round 4
// 1773.532 us; speedup vs baseline: 3.4565x; 1.3531x over previous
//
#include <hip/hip_runtime.h>
#include <hip/hip_bf16.h>
#include <math.h>

using short8 = __attribute__((ext_vector_type(8))) short;
using f32x4  = __attribute__((ext_vector_type(4))) float;

// ---------- helpers ----------
__device__ __forceinline__ float bf2f(unsigned short u) {
    return __uint_as_float(((unsigned int)u) << 16);
}
__device__ __forceinline__ unsigned short f2bf(float f) {
    unsigned int x = __float_as_uint(f);
    return (unsigned short)((x + 0x7fffu + ((x >> 16) & 1u)) >> 16);
}
__device__ __forceinline__ void storeS(float* p, float v) { *p = v; }
__device__ __forceinline__ void storeS(unsigned short* p, float v) { *p = f2bf(v); }

// ---------- build fused per-edge-type projection weights (f32, [k][n]) ----------
__global__ __launch_bounds__(256) void build_eff(
    const float* __restrict__ Wk, const float* __restrict__ Wv,
    const float* __restrict__ att_w, const float* __restrict__ val_w,
    float* __restrict__ eff)
{
    int gid = blockIdx.x;          // 0 .. 6*256-1
    int mat = gid >> 8;            // 0..5
    int k = gid & 255;
    int e = mat >> 1, which = mat & 1;
    int ts = (e == 0) ? 0 : 1;
    int c = threadIdx.x;           // 0..255
    int h = c >> 5, j = c & 31;
    const float* Wsrc = (which == 0 ? Wk : Wv) + ((size_t)ts * 256 + k) * 256 + h * 32;
    const float* aw = (which == 0 ? att_w : val_w) + (size_t)((e * 8 + h) * 32) * 32 + j;
    float s = 0.f;
    #pragma unroll
    for (int d = 0; d < 32; ++d) s += Wsrc[d] * aw[d * 32];
    eff[((size_t)mat * 256 + k) * 256 + c] = s;
}

__global__ void build_eff_bias(
    const float* __restrict__ bk, const float* __restrict__ bv,
    const float* __restrict__ att_w, const float* __restrict__ val_w,
    float* __restrict__ effb)
{
    int mat = blockIdx.x;          // 0..5
    int c = threadIdx.x;           // 0..255
    int e = mat >> 1, which = mat & 1;
    int ts = (e == 0) ? 0 : 1;
    int h = c >> 5, j = c & 31;
    const float* bsrc = (which == 0 ? bk : bv) + ts * 256 + h * 32;
    const float* aw = (which == 0 ? att_w : val_w) + (size_t)((e * 8 + h) * 32) * 32 + j;
    float s = 0.f;
    #pragma unroll
    for (int d = 0; d < 32; ++d) s += bsrc[d] * aw[d * 32];
    effb[mat * 256 + c] = s;
}

// ---------- transpose + cast: dst[n][k] = bf16(src[k][n]), 256x256 ----------
__global__ __launch_bounds__(256) void transpose_cast_bf16(
    const float* __restrict__ src, unsigned short* __restrict__ dst)
{
    __shared__ float tile[32][33];
    int bx = blockIdx.x & 7, by = blockIdx.x >> 3;
    int tx = threadIdx.x & 31, ty = threadIdx.x >> 5;
    #pragma unroll
    for (int i = 0; i < 4; ++i)
        tile[ty + i * 8][tx] = src[(size_t)(by * 32 + ty + i * 8) * 256 + bx * 32 + tx];
    __syncthreads();
    #pragma unroll
    for (int i = 0; i < 4; ++i)
        dst[(size_t)(bx * 32 + ty + i * 8) * 256 + by * 32 + tx] = f2bf(tile[tx][ty + i * 8]);
}

// ---------- f32 -> bf16 elementwise cast ----------
__global__ void cast_bf16(const float* __restrict__ in, unsigned short* __restrict__ out, int n4) {
    int i = blockIdx.x * 256 + threadIdx.x;
    if (i < n4) {
        float4 v = ((const float4*)in)[i];
        ushort4 o; o.x = f2bf(v.x); o.y = f2bf(v.y); o.z = f2bf(v.z); o.w = f2bf(v.w);
        ((ushort4*)out)[i] = o;
    }
}

// ---------- MFMA GEMM: C[M,256] = A[M,256](bf16) @ W(bf16, Wt[n][k]) (+bias) ----------
// 128x256 tile, BK=32, 4 waves (32 rows each), mfma_f32_16x16x32_bf16
template <typename OutT>
__global__ __launch_bounds__(256) void mfma_gemm(
    const unsigned short* __restrict__ A,
    const unsigned short* __restrict__ Wt,
    const float* __restrict__ bias,
    OutT* __restrict__ C, int M)
{
    __shared__ unsigned short As[128 * 40];   // rows padded to 40 elems (80 B)
    __shared__ unsigned short Bs[256 * 40];
    int t = threadIdx.x;
    int w = t >> 6, l = t & 63;
    int lr = l & 15, lg = l >> 4;
    int m0 = blockIdx.x * 128;

    f32x4 acc0[16] = {};   // rows m0 + w*32 + lg*4+r
    f32x4 acc1[16] = {};   // rows +16

    int ar = t >> 1;               // tile row 0..127
    int ah = (t & 1) * 16;         // k-half (elements)
    bool aok = (m0 + ar) < M;
    const unsigned short* Ap = A + (size_t)(m0 + ar) * 256 + ah;
    const unsigned short* Wp = Wt + (size_t)t * 256;

    for (int k0 = 0; k0 < 256; k0 += 32) {
        uint4 av0 = {0,0,0,0}, av1 = {0,0,0,0};
        if (aok) {
            av0 = *(const uint4*)(Ap + k0);
            av1 = *(const uint4*)(Ap + k0 + 8);
        }
        uint4 b0 = *(const uint4*)(Wp + k0);
        uint4 b1 = *(const uint4*)(Wp + k0 + 8);
        uint4 b2 = *(const uint4*)(Wp + k0 + 16);
        uint4 b3 = *(const uint4*)(Wp + k0 + 24);
        __syncthreads();
        *(uint4*)&As[ar * 40 + ah]     = av0;
        *(uint4*)&As[ar * 40 + ah + 8] = av1;
        *(uint4*)&Bs[t * 40 + 0]  = b0;
        *(uint4*)&Bs[t * 40 + 8]  = b1;
        *(uint4*)&Bs[t * 40 + 16] = b2;
        *(uint4*)&Bs[t * 40 + 24] = b3;
        __syncthreads();
        short8 a0 = *(const short8*)&As[(w * 32 + lr) * 40 + lg * 8];
        short8 a1 = *(const short8*)&As[(w * 32 + 16 + lr) * 40 + lg * 8];
        #pragma unroll
        for (int nf = 0; nf < 16; ++nf) {
            short8 b = *(const short8*)&Bs[(nf * 16 + lr) * 40 + lg * 8];
            acc0[nf] = __builtin_amdgcn_mfma_f32_16x16x32_bf16(a0, b, acc0[nf], 0, 0, 0);
            acc1[nf] = __builtin_amdgcn_mfma_f32_16x16x32_bf16(a1, b, acc1[nf], 0, 0, 0);
        }
    }

    #pragma unroll
    for (int nf = 0; nf < 16; ++nf) {
        int n = nf * 16 + lr;
        float bval = bias ? bias[n] : 0.f;
        #pragma unroll
        for (int r = 0; r < 4; ++r) {
            int row0 = m0 + w * 32 + lg * 4 + r;
            int row1 = row0 + 16;
            if (row0 < M) storeS(C + (size_t)row0 * 256 + n, acc0[nf][r] + bval);
            if (row1 < M) storeS(C + (size_t)row1 * 256 + n, acc1[nf][r] + bval);
        }
    }
}

// ---------- CSR build: histogram + scan + scatter ----------
__global__ void k_hist(const int* __restrict__ dst, int E, int* __restrict__ cnt) {
    int e = blockIdx.x * 256 + threadIdx.x;
    if (e < E) atomicAdd(&cnt[dst[e]], 1);
}

__global__ __launch_bounds__(256) void k_scan1(
    const int* __restrict__ cnt, int* __restrict__ offs, int* __restrict__ blksum, int N)
{
    __shared__ int sm[256];
    int t = threadIdx.x, i = blockIdx.x * 256 + t;
    int x = (i < N) ? cnt[i] : 0;
    sm[t] = x; __syncthreads();
    int v = x;
    #pragma unroll
    for (int off = 1; off < 256; off <<= 1) {
        int y = (t >= off) ? sm[t - off] : 0;
        __syncthreads();
        v += y; sm[t] = v;
        __syncthreads();
    }
    if (i < N) offs[i] = v - x;
    if (t == 255) blksum[blockIdx.x] = v;
}

__global__ __launch_bounds__(512) void k_scan2(int* __restrict__ blksum, int nb) {
    __shared__ int sm[512];
    int t = threadIdx.x;
    int x = (t < nb) ? blksum[t] : 0;
    sm[t] = x; __syncthreads();
    int v = x;
    #pragma unroll
    for (int off = 1; off < 512; off <<= 1) {
        int y = (t >= off) ? sm[t - off] : 0;
        __syncthreads();
        v += y; sm[t] = v;
        __syncthreads();
    }
    if (t < nb) blksum[t] = v - x;
}

__global__ void k_scan3(int* __restrict__ offs, int* __restrict__ cursor,
                        const int* __restrict__ blksum, int N)
{
    int i = blockIdx.x * 256 + threadIdx.x;
    if (i < N) {
        int v = offs[i] + blksum[i >> 8];
        offs[i] = v;
        cursor[i] = v;
    }
}

__global__ void k_scatter(const int* __restrict__ src, const int* __restrict__ dst, int E,
                          int* __restrict__ cursor, int* __restrict__ ssrc)
{
    int e = blockIdx.x * 256 + threadIdx.x;
    if (e < E) {
        int pos = atomicAdd(&cursor[dst[e]], 1);
        ssrc[pos] = src[e];
    }
}

// ---------- CSR aggregation: one wave per destination node ----------
__global__ __launch_bounds__(256) void csr_agg(
    const int* __restrict__ offs, const int* __restrict__ cnt,
    const int* __restrict__ ssrc,
    const unsigned short* __restrict__ q,    // [Nd,256] bf16
    const unsigned short* __restrict__ ke,   // [Ns,256] bf16
    const unsigned short* __restrict__ ve,   // [Ns,256] bf16
    const float* __restrict__ canon,         // [8]
    float rsdk,
    const unsigned short* __restrict__ other,
    unsigned short* __restrict__ out, int N)
{
    int wave = threadIdx.x >> 6, lane = threadIdx.x & 63;
    int n = blockIdx.x * 4 + wave;
    if (n >= N) return;
    ushort4 qv = *(const ushort4*)(q + (size_t)n * 256 + lane * 4);
    float q0 = bf2f(qv.x), q1 = bf2f(qv.y), q2 = bf2f(qv.z), q3 = bf2f(qv.w);
    int base = offs[n], deg = cnt[n];
    int h = lane >> 3;
    float cw = canon[h] * rsdk;
    float den = 0.f, a0 = 0.f, a1 = 0.f, a2 = 0.f, a3 = 0.f;
    for (int i = 0; i < deg; ++i) {
        int s = ssrc[base + i];
        ushort4 kv = *(const ushort4*)(ke + (size_t)s * 256 + lane * 4);
        float p = q0 * bf2f(kv.x) + q1 * bf2f(kv.y) + q2 * bf2f(kv.z) + q3 * bf2f(kv.w);
        p += __shfl_xor(p, 1);
        p += __shfl_xor(p, 2);
        p += __shfl_xor(p, 4);
        float ex = __expf(p * cw);
        ushort4 vv = *(const ushort4*)(ve + (size_t)s * 256 + lane * 4);
        den += ex;
        a0 += ex * bf2f(vv.x);
        a1 += ex * bf2f(vv.y);
        a2 += ex * bf2f(vv.z);
        a3 += ex * bf2f(vv.w);
    }
    float r = den > 0.f ? 1.f / den : 0.f;
    a0 *= r; a1 *= r; a2 *= r; a3 *= r;
    if (other) {
        ushort4 ov = ((const ushort4*)(other + (size_t)n * 256))[lane];
        a0 = 0.5f * (a0 + bf2f(ov.x));
        a1 = 0.5f * (a1 + bf2f(ov.y));
        a2 = 0.5f * (a2 + bf2f(ov.z));
        a3 = 0.5f * (a3 + bf2f(ov.w));
    }
    ushort4 o4; o4.x = f2bf(a0); o4.y = f2bf(a1); o4.z = f2bf(a2); o4.w = f2bf(a3);
    ((ushort4*)(out + (size_t)n * 256))[lane] = o4;
}

// ---------- residual gate + LayerNorm (one wave per row) ----------
__global__ __launch_bounds__(256) void finalize_ln(
    const float* __restrict__ pre,   // [N,256] = t @ Wfc
    const float* __restrict__ hin,   // [N,256]
    const float* __restrict__ bfc, const float* __restrict__ g,
    const float* __restrict__ b, const float* __restrict__ res, int nid,
    float* __restrict__ out, int N)
{
    int wave = threadIdx.x >> 6, lane = threadIdx.x & 63;
    int row = blockIdx.x * 4 + wave;
    if (row >= N) return;
    float alpha = 1.f / (1.f + __expf(-res[nid]));
    float beta = 1.f - alpha;
    float4 pv = ((const float4*)(pre + (size_t)row * 256))[lane];
    float4 hv = ((const float4*)(hin + (size_t)row * 256))[lane];
    float4 bv = ((const float4*)bfc)[lane];
    float hp0 = (pv.x + bv.x) * alpha + hv.x * beta;
    float hp1 = (pv.y + bv.y) * alpha + hv.y * beta;
    float hp2 = (pv.z + bv.z) * alpha + hv.z * beta;
    float hp3 = (pv.w + bv.w) * alpha + hv.w * beta;
    float s = hp0 + hp1 + hp2 + hp3;
    float s2 = hp0 * hp0 + hp1 * hp1 + hp2 * hp2 + hp3 * hp3;
    #pragma unroll
    for (int off = 1; off < 64; off <<= 1) {
        s  += __shfl_xor(s, off);
        s2 += __shfl_xor(s2, off);
    }
    float mu = s * (1.f / 256.f);
    float var = s2 * (1.f / 256.f) - mu * mu;
    float rstd = rsqrtf(var + 1e-5f);
    float4 gv = ((const float4*)g)[lane];
    float4 bbv = ((const float4*)b)[lane];
    float4 o;
    o.x = (hp0 - mu) * rstd * gv.x + bbv.x;
    o.y = (hp1 - mu) * rstd * gv.y + bbv.y;
    o.z = (hp2 - mu) * rstd * gv.z + bbv.z;
    o.w = (hp3 - mu) * rstd * gv.w + bbv.w;
    ((float4*)(out + (size_t)row * 256))[lane] = o;
}

// ---------- launch ----------
extern "C" void kernel_launch(void* const* d_in, const int* in_sizes, int n_in,
                              void* d_out, int out_size, void* d_ws, size_t ws_size,
                              hipStream_t stream)
{
    const float* h_a   = (const float*)d_in[0];
    const float* h_p   = (const float*)d_in[1];
    const int* w_src   = (const int*)d_in[2];
    const int* w_dst   = (const int*)d_in[3];
    const int* wb_src  = (const int*)d_in[4];
    const int* wb_dst  = (const int*)d_in[5];
    const int* c_src   = (const int*)d_in[6];
    const int* c_dst   = (const int*)d_in[7];
    const float* Wk    = (const float*)d_in[8];
    const float* bk    = (const float*)d_in[9];
    const float* Wq    = (const float*)d_in[10];
    const float* bq    = (const float*)d_in[11];
    const float* Wv    = (const float*)d_in[12];
    const float* bv    = (const float*)d_in[13];
    const float* Wfc   = (const float*)d_in[14];
    const float* bfc   = (const float*)d_in[15];
    const float* ln_g  = (const float*)d_in[16];
    const float* ln_b  = (const float*)d_in[17];
    const float* att_w = (const float*)d_in[18];
    const float* val_w = (const float*)d_in[19];
    const float* canon = (const float*)d_in[20];
    const float* res   = (const float*)d_in[21];

    const int NA = in_sizes[0] / 256;
    const int NP = in_sizes[1] / 256;
    const int E0 = in_sizes[2];
    const int E1 = in_sizes[4];
    const int E2 = in_sizes[6];
    const int Nmax = NA > NP ? NA : NP;
    int Emax = E0 > E1 ? E0 : E1; if (E2 > Emax) Emax = E2;

    // workspace layout
    char* p = (char*)d_ws;
    auto alloc = [&](size_t bytes) -> char* {
        char* r = p;
        p += (bytes + 255) & ~(size_t)255;
        return r;
    };
    float* eff_w = (float*)alloc((size_t)6 * 65536 * 4);
    float* eff_b = (float*)alloc(6 * 256 * 4);
    unsigned short* wt = (unsigned short*)alloc((size_t)10 * 65536 * 2); // 0-5 effT, 6-7 WqT, 8-9 WfcT
    unsigned short* ha_bf = (unsigned short*)alloc((size_t)NA * 256 * 2);
    unsigned short* hp_bf = (unsigned short*)alloc((size_t)NP * 256 * 2);
    unsigned short* qa  = (unsigned short*)alloc((size_t)NA * 256 * 2);
    unsigned short* qp  = (unsigned short*)alloc((size_t)NP * 256 * 2);
    unsigned short* keb = (unsigned short*)alloc((size_t)Nmax * 256 * 2);
    unsigned short* veb = (unsigned short*)alloc((size_t)Nmax * 256 * 2);
    unsigned short* agg_w  = (unsigned short*)alloc((size_t)NP * 256 * 2);  // t_paper
    unsigned short* agg_wb = (unsigned short*)alloc((size_t)NA * 256 * 2);  // t_author
    int* cnt    = (int*)alloc((size_t)Nmax * 4);
    int* offs   = (int*)alloc((size_t)Nmax * 4);
    int* cursor = (int*)alloc((size_t)Nmax * 4);
    int* blksum = (int*)alloc(512 * 4);
    int* ssrc   = (int*)alloc((size_t)Emax * 4);

    const float rsdk = 0.17677669529663687f;  // 1/sqrt(32)

    // ---- prep: fused weights, transposed bf16 weights, bf16 features ----
    build_eff<<<dim3(6 * 256), 256, 0, stream>>>(Wk, Wv, att_w, val_w, eff_w);
    build_eff_bias<<<6, 256, 0, stream>>>(bk, bv, att_w, val_w, eff_b);
    for (int m = 0; m < 6; ++m)
        transpose_cast_bf16<<<64, 256, 0, stream>>>(eff_w + (size_t)m * 65536, wt + (size_t)m * 65536);
    transpose_cast_bf16<<<64, 256, 0, stream>>>(Wq,          wt + (size_t)6 * 65536);
    transpose_cast_bf16<<<64, 256, 0, stream>>>(Wq + 65536,  wt + (size_t)7 * 65536);
    transpose_cast_bf16<<<64, 256, 0, stream>>>(Wfc,         wt + (size_t)8 * 65536);
    transpose_cast_bf16<<<64, 256, 0, stream>>>(Wfc + 65536, wt + (size_t)9 * 65536);
    cast_bf16<<<(NA * 64 + 255) / 256, 256, 0, stream>>>(h_a, ha_bf, NA * 64);
    cast_bf16<<<(NP * 64 + 255) / 256, 256, 0, stream>>>(h_p, hp_bf, NP * 64);

    int gA = (NA + 127) / 128, gP = (NP + 127) / 128;

    // q projections
    mfma_gemm<unsigned short><<<gA, 256, 0, stream>>>(ha_bf, wt + (size_t)6 * 65536, bq,        qa, NA);
    mfma_gemm<unsigned short><<<gP, 256, 0, stream>>>(hp_bf, wt + (size_t)7 * 65536, bq + 256,  qp, NP);

    auto run_etype = [&](const int* esrc, const int* edst, int E, int Nd,
                         const unsigned short* qn, const float* canon_e,
                         const unsigned short* other, unsigned short* out) {
        hipMemsetAsync(cnt, 0, (size_t)Nd * 4, stream);
        int gE = (E + 255) / 256, gN = (Nd + 255) / 256;
        k_hist<<<gE, 256, 0, stream>>>(edst, E, cnt);
        k_scan1<<<gN, 256, 0, stream>>>(cnt, offs, blksum, Nd);
        k_scan2<<<1, 512, 0, stream>>>(blksum, gN);
        k_scan3<<<gN, 256, 0, stream>>>(offs, cursor, blksum, Nd);
        k_scatter<<<gE, 256, 0, stream>>>(esrc, edst, E, cursor, ssrc);
        csr_agg<<<(Nd + 3) / 4, 256, 0, stream>>>(offs, cnt, ssrc, qn, keb, veb,
                                                  canon_e, rsdk, other, out, Nd);
    };

    // etype 0: writes (author -> paper), q = q_p
    mfma_gemm<unsigned short><<<gA, 256, 0, stream>>>(ha_bf, wt,                     eff_b,       keb, NA);
    mfma_gemm<unsigned short><<<gA, 256, 0, stream>>>(ha_bf, wt + (size_t)1 * 65536, eff_b + 256, veb, NA);
    run_etype(w_src, w_dst, E0, NP, qp, canon, nullptr, agg_w);

    // etype 1: written-by (paper -> author), q = q_a
    mfma_gemm<unsigned short><<<gP, 256, 0, stream>>>(hp_bf, wt + (size_t)2 * 65536, eff_b + 512, keb, NP);
    mfma_gemm<unsigned short><<<gP, 256, 0, stream>>>(hp_bf, wt + (size_t)3 * 65536, eff_b + 768, veb, NP);
    run_etype(wb_src, wb_dst, E1, NA, qa, canon + 8, nullptr, agg_wb);

    // etype 2: cites (paper -> paper), q = q_p; fuse cross-etype mean with etype0
    mfma_gemm<unsigned short><<<gP, 256, 0, stream>>>(hp_bf, wt + (size_t)4 * 65536, eff_b + 1024, keb, NP);
    mfma_gemm<unsigned short><<<gP, 256, 0, stream>>>(hp_bf, wt + (size_t)5 * 65536, eff_b + 1280, veb, NP);
    run_etype(c_src, c_dst, E2, NP, qp, canon + 16, agg_w, agg_w);

    // output GEMMs (f32 out); alias freed bf16 buffers as f32 scratch
    float* pre_a = (float*)keb;  // keb+veb: 2*Nmax*256*2 bytes >= NA*256*4
    float* pre_p = (float*)qa;   // qa+qp:   (NA+NP)*256*2 bytes >= NP*256*4
    mfma_gemm<float><<<gA, 256, 0, stream>>>(agg_wb, wt + (size_t)8 * 65536, nullptr, pre_a, NA);
    mfma_gemm<float><<<gP, 256, 0, stream>>>(agg_w,  wt + (size_t)9 * 65536, nullptr, pre_p, NP);

    // residual gate + LayerNorm
    finalize_ln<<<(NA + 3) / 4, 256, 0, stream>>>(pre_a, h_a, bfc, ln_g, ln_b, res, 0,
                                                  (float*)d_out, NA);
    finalize_ln<<<(NP + 3) / 4, 256, 0, stream>>>(pre_p, h_p, bfc + 256, ln_g + 256, ln_b + 256, res, 1,
                                                  (float*)d_out + (size_t)NA * 256, NP);
}

// Round 5
// 1096.621 us; speedup vs baseline: 5.5900x; 1.6173x over previous
//
#include <hip/hip_runtime.h>
#include <hip/hip_bf16.h>
#include <math.h>

using short8 = __attribute__((ext_vector_type(8))) short;
using f32x4  = __attribute__((ext_vector_type(4))) float;

// ---------- helpers ----------
__device__ __forceinline__ float bf2f(unsigned short u) {
    return __uint_as_float(((unsigned int)u) << 16);
}
__device__ __forceinline__ unsigned short f2bf(float f) {
    unsigned int x = __float_as_uint(f);
    return (unsigned short)((x + 0x7fffu + ((x >> 16) & 1u)) >> 16);
}
__device__ __forceinline__ void storeS(float* p, float v) { *p = v; }
__device__ __forceinline__ void storeS(unsigned short* p, float v) { *p = f2bf(v); }

// ---------- build fused per-edge-type projection weights (f32, [k][n]) ----------
__global__ __launch_bounds__(256) void build_eff(
    const float* __restrict__ Wk, const float* __restrict__ Wv,
    const float* __restrict__ att_w, const float* __restrict__ val_w,
    float* __restrict__ eff)
{
    int gid = blockIdx.x;          // 0 .. 6*256-1
    int mat = gid >> 8;            // 0..5
    int k = gid & 255;
    int e = mat >> 1, which = mat & 1;
    int ts = (e == 0) ? 0 : 1;
    int c = threadIdx.x;           // 0..255
    int h = c >> 5, j = c & 31;
    const float* Wsrc = (which == 0 ? Wk : Wv) + ((size_t)ts * 256 + k) * 256 + h * 32;
    const float* aw = (which == 0 ? att_w : val_w) + (size_t)((e * 8 + h) * 32) * 32 + j;
    float s = 0.f;
    #pragma unroll
    for (int d = 0; d < 32; ++d) s += Wsrc[d] * aw[d * 32];
    eff[((size_t)mat * 256 + k) * 256 + c] = s;
}

__global__ void build_eff_bias(
    const float* __restrict__ bk, const float* __restrict__ bv,
    const float* __restrict__ att_w, const float* __restrict__ val_w,
    float* __restrict__ effb)
{
    int mat = blockIdx.x;          // 0..5
    int c = threadIdx.x;           // 0..255
    int e = mat >> 1, which = mat & 1;
    int ts = (e == 0) ? 0 : 1;
    int h = c >> 5, j = c & 31;
    const float* bsrc = (which == 0 ? bk : bv) + ts * 256 + h * 32;
    const float* aw = (which == 0 ? att_w : val_w) + (size_t)((e * 8 + h) * 32) * 32 + j;
    float s = 0.f;
    #pragma unroll
    for (int d = 0; d < 32; ++d) s += bsrc[d] * aw[d * 32];
    effb[mat * 256 + c] = s;
}

// ---------- transpose + cast: dst[n][k] = bf16(src[k][n]), 256x256 ----------
__global__ __launch_bounds__(256) void transpose_cast_bf16(
    const float* __restrict__ src, unsigned short* __restrict__ dst)
{
    __shared__ float tile[32][33];
    int bx = blockIdx.x & 7, by = blockIdx.x >> 3;
    int tx = threadIdx.x & 31, ty = threadIdx.x >> 5;
    #pragma unroll
    for (int i = 0; i < 4; ++i)
        tile[ty + i * 8][tx] = src[(size_t)(by * 32 + ty + i * 8) * 256 + bx * 32 + tx];
    __syncthreads();
    #pragma unroll
    for (int i = 0; i < 4; ++i)
        dst[(size_t)(bx * 32 + ty + i * 8) * 256 + by * 32 + tx] = f2bf(tile[tx][ty + i * 8]);
}

// ---------- f32 -> bf16 elementwise cast ----------
__global__ void cast_bf16(const float* __restrict__ in, unsigned short* __restrict__ out, int n4) {
    int i = blockIdx.x * 256 + threadIdx.x;
    if (i < n4) {
        float4 v = ((const float4*)in)[i];
        ushort4 o; o.x = f2bf(v.x); o.y = f2bf(v.y); o.z = f2bf(v.z); o.w = f2bf(v.w);
        ((ushort4*)out)[i] = o;
    }
}

// ---------- MFMA GEMM: C[M,256] = A[M,256](bf16) @ W(bf16, Wt[n][k]) (+bias) ----------
// 512 threads / 8 waves; block tile 128x256; wave tile 32x128 (acc = 64 VGPR);
// BK=64, register prefetch of next k-step issued before the MFMA phase.
// LDS rows padded to 72 elems (144 B, odd multiple of 16B -> near-uniform banks).
template <typename OutT>
__global__ __launch_bounds__(512, 4) void mfma_gemm(
    const unsigned short* __restrict__ A,
    const unsigned short* __restrict__ Wt,
    const float* __restrict__ bias,
    OutT* __restrict__ C, int M)
{
    __shared__ unsigned short As[128 * 72];
    __shared__ unsigned short Bs[256 * 72];
    int t = threadIdx.x;
    int w = t >> 6, l = t & 63;
    int lr = l & 15, lg = l >> 4;
    int wr = w >> 1, wc = w & 1;     // wave row-group (32 rows), col half (128)
    int m0 = blockIdx.x * 128;

    f32x4 acc0[8] = {};   // rows wr*32 + lg*4 + r
    f32x4 acc1[8] = {};   // rows +16

    // staging: A: thread t -> row t>>2, elem chunk (t&3)*16 (32 B)
    int ar = t >> 2, ac = (t & 3) * 16;
    bool aok = (m0 + ar) < M;
    const unsigned short* Ap = A + (size_t)(m0 + ar) * 256 + ac;
    // B: thread t -> row t>>1, elem chunk (t&1)*32 (64 B)
    int br = t >> 1, bc = (t & 1) * 32;
    const unsigned short* Bp = Wt + (size_t)br * 256 + bc;

    uint4 a0 = {0,0,0,0}, a1 = {0,0,0,0};
    if (aok) { a0 = *(const uint4*)(Ap); a1 = *(const uint4*)(Ap + 8); }
    uint4 b0 = *(const uint4*)(Bp),      b1 = *(const uint4*)(Bp + 8),
          b2 = *(const uint4*)(Bp + 16), b3 = *(const uint4*)(Bp + 24);

    for (int step = 0; step < 4; ++step) {
        __syncthreads();
        *(uint4*)&As[ar * 72 + ac]      = a0;
        *(uint4*)&As[ar * 72 + ac + 8]  = a1;
        *(uint4*)&Bs[br * 72 + bc]      = b0;
        *(uint4*)&Bs[br * 72 + bc + 8]  = b1;
        *(uint4*)&Bs[br * 72 + bc + 16] = b2;
        *(uint4*)&Bs[br * 72 + bc + 24] = b3;
        __syncthreads();
        if (step < 3) {
            int k0 = (step + 1) * 64;
            if (aok) { a0 = *(const uint4*)(Ap + k0); a1 = *(const uint4*)(Ap + k0 + 8); }
            b0 = *(const uint4*)(Bp + k0);      b1 = *(const uint4*)(Bp + k0 + 8);
            b2 = *(const uint4*)(Bp + k0 + 16); b3 = *(const uint4*)(Bp + k0 + 24);
        }
        #pragma unroll
        for (int kk = 0; kk < 64; kk += 32) {
            short8 fa0 = *(const short8*)&As[(wr * 32 + lr) * 72 + kk + lg * 8];
            short8 fa1 = *(const short8*)&As[(wr * 32 + 16 + lr) * 72 + kk + lg * 8];
            #pragma unroll
            for (int nf = 0; nf < 8; ++nf) {
                short8 fb = *(const short8*)&Bs[(wc * 128 + nf * 16 + lr) * 72 + kk + lg * 8];
                acc0[nf] = __builtin_amdgcn_mfma_f32_16x16x32_bf16(fa0, fb, acc0[nf], 0, 0, 0);
                acc1[nf] = __builtin_amdgcn_mfma_f32_16x16x32_bf16(fa1, fb, acc1[nf], 0, 0, 0);
            }
        }
    }

    #pragma unroll
    for (int nf = 0; nf < 8; ++nf) {
        int n = wc * 128 + nf * 16 + lr;
        float bval = bias ? bias[n] : 0.f;
        #pragma unroll
        for (int r = 0; r < 4; ++r) {
            int row0 = m0 + wr * 32 + lg * 4 + r;
            int row1 = row0 + 16;
            if (row0 < M) storeS(C + (size_t)row0 * 256 + n, acc0[nf][r] + bval);
            if (row1 < M) storeS(C + (size_t)row1 * 256 + n, acc1[nf][r] + bval);
        }
    }
}

// ---------- CSR build: histogram + scan + scatter ----------
__global__ void k_hist(const int* __restrict__ dst, int E, int* __restrict__ cnt) {
    int e = blockIdx.x * 256 + threadIdx.x;
    if (e < E) atomicAdd(&cnt[dst[e]], 1);
}

__global__ __launch_bounds__(256) void k_scan1(
    const int* __restrict__ cnt, int* __restrict__ offs, int* __restrict__ blksum, int N)
{
    __shared__ int sm[256];
    int t = threadIdx.x, i = blockIdx.x * 256 + t;
    int x = (i < N) ? cnt[i] : 0;
    sm[t] = x; __syncthreads();
    int v = x;
    #pragma unroll
    for (int off = 1; off < 256; off <<= 1) {
        int y = (t >= off) ? sm[t - off] : 0;
        __syncthreads();
        v += y; sm[t] = v;
        __syncthreads();
    }
    if (i < N) offs[i] = v - x;
    if (t == 255) blksum[blockIdx.x] = v;
}

__global__ __launch_bounds__(512) void k_scan2(int* __restrict__ blksum, int nb) {
    __shared__ int sm[512];
    int t = threadIdx.x;
    int x = (t < nb) ? blksum[t] : 0;
    sm[t] = x; __syncthreads();
    int v = x;
    #pragma unroll
    for (int off = 1; off < 512; off <<= 1) {
        int y = (t >= off) ? sm[t - off] : 0;
        __syncthreads();
        v += y; sm[t] = v;
        __syncthreads();
    }
    if (t < nb) blksum[t] = v - x;
}

__global__ void k_scan3(int* __restrict__ offs, int* __restrict__ cursor,
                        const int* __restrict__ blksum, int N)
{
    int i = blockIdx.x * 256 + threadIdx.x;
    if (i < N) {
        int v = offs[i] + blksum[i >> 8];
        offs[i] = v;
        cursor[i] = v;
    }
}

__global__ void k_scatter(const int* __restrict__ src, const int* __restrict__ dst, int E,
                          int* __restrict__ cursor, int* __restrict__ ssrc)
{
    int e = blockIdx.x * 256 + threadIdx.x;
    if (e < E) {
        int pos = atomicAdd(&cursor[dst[e]], 1);
        ssrc[pos] = src[e];
    }
}

// ---------- CSR aggregation: one wave per destination node ----------
__global__ __launch_bounds__(256) void csr_agg(
    const int* __restrict__ offs, const int* __restrict__ cnt,
    const int* __restrict__ ssrc,
    const unsigned short* __restrict__ q,    // [Nd,256] bf16
    const unsigned short* __restrict__ ke,   // [Ns,256] bf16
    const unsigned short* __restrict__ ve,   // [Ns,256] bf16
    const float* __restrict__ canon,         // [8]
    float rsdk,
    const unsigned short* __restrict__ other,
    unsigned short* __restrict__ out, int N)
{
    int wave = threadIdx.x >> 6, lane = threadIdx.x & 63;
    int n = blockIdx.x * 4 + wave;
    if (n >= N) return;
    ushort4 qv = *(const ushort4*)(q + (size_t)n * 256 + lane * 4);
    float q0 = bf2f(qv.x), q1 = bf2f(qv.y), q2 = bf2f(qv.z), q3 = bf2f(qv.w);
    int base = offs[n], deg = cnt[n];
    int h = lane >> 3;
    float cw = canon[h] * rsdk;
    float den = 0.f, a0 = 0.f, a1 = 0.f, a2 = 0.f, a3 = 0.f;
    for (int i = 0; i < deg; ++i) {
        int s = ssrc[base + i];
        ushort4 kv = *(const ushort4*)(ke + (size_t)s * 256 + lane * 4);
        float p = q0 * bf2f(kv.x) + q1 * bf2f(kv.y) + q2 * bf2f(kv.z) + q3 * bf2f(kv.w);
        p += __shfl_xor(p, 1);
        p += __shfl_xor(p, 2);
        p += __shfl_xor(p, 4);
        float ex = __expf(p * cw);
        ushort4 vv = *(const ushort4*)(ve + (size_t)s * 256 + lane * 4);
        den += ex;
        a0 += ex * bf2f(vv.x);
        a1 += ex * bf2f(vv.y);
        a2 += ex * bf2f(vv.z);
        a3 += ex * bf2f(vv.w);
    }
    float r = den > 0.f ? 1.f / den : 0.f;
    a0 *= r; a1 *= r; a2 *= r; a3 *= r;
    if (other) {
        ushort4 ov = ((const ushort4*)(other + (size_t)n * 256))[lane];
        a0 = 0.5f * (a0 + bf2f(ov.x));
        a1 = 0.5f * (a1 + bf2f(ov.y));
        a2 = 0.5f * (a2 + bf2f(ov.z));
        a3 = 0.5f * (a3 + bf2f(ov.w));
    }
    ushort4 o4; o4.x = f2bf(a0); o4.y = f2bf(a1); o4.z = f2bf(a2); o4.w = f2bf(a3);
    ((ushort4*)(out + (size_t)n * 256))[lane] = o4;
}

// ---------- residual gate + LayerNorm (one wave per row) ----------
__global__ __launch_bounds__(256) void finalize_ln(
    const float* __restrict__ pre,   // [N,256] = t @ Wfc
    const float* __restrict__ hin,   // [N,256]
    const float* __restrict__ bfc, const float* __restrict__ g,
    const float* __restrict__ b, const float* __restrict__ res, int nid,
    float* __restrict__ out, int N)
{
    int wave = threadIdx.x >> 6, lane = threadIdx.x & 63;
    int row = blockIdx.x * 4 + wave;
    if (row >= N) return;
    float alpha = 1.f / (1.f + __expf(-res[nid]));
    float beta = 1.f - alpha;
    float4 pv = ((const float4*)(pre + (size_t)row * 256))[lane];
    float4 hv = ((const float4*)(hin + (size_t)row * 256))[lane];
    float4 bv = ((const float4*)bfc)[lane];
    float hp0 = (pv.x + bv.x) * alpha + hv.x * beta;
    float hp1 = (pv.y + bv.y) * alpha + hv.y * beta;
    float hp2 = (pv.z + bv.z) * alpha + hv.z * beta;
    float hp3 = (pv.w + bv.w) * alpha + hv.w * beta;
    float s = hp0 + hp1 + hp2 + hp3;
    float s2 = hp0 * hp0 + hp1 * hp1 + hp2 * hp2 + hp3 * hp3;
    #pragma unroll
    for (int off = 1; off < 64; off <<= 1) {
        s  += __shfl_xor(s, off);
        s2 += __shfl_xor(s2, off);
    }
    float mu = s * (1.f / 256.f);
    float var = s2 * (1.f / 256.f) - mu * mu;
    float rstd = rsqrtf(var + 1e-5f);
    float4 gv = ((const float4*)g)[lane];
    float4 bbv = ((const float4*)b)[lane];
    float4 o;
    o.x = (hp0 - mu) * rstd * gv.x + bbv.x;
    o.y = (hp1 - mu) * rstd * gv.y + bbv.y;
    o.z = (hp2 - mu) * rstd * gv.z + bbv.z;
    o.w = (hp3 - mu) * rstd * gv.w + bbv.w;
    ((float4*)(out + (size_t)row * 256))[lane] = o;
}

// ---------- launch ----------
extern "C" void kernel_launch(void* const* d_in, const int* in_sizes, int n_in,
                              void* d_out, int out_size, void* d_ws, size_t ws_size,
                              hipStream_t stream)
{
    const float* h_a   = (const float*)d_in[0];
    const float* h_p   = (const float*)d_in[1];
    const int* w_src   = (const int*)d_in[2];
    const int* w_dst   = (const int*)d_in[3];
    const int* wb_src  = (const int*)d_in[4];
    const int* wb_dst  = (const int*)d_in[5];
    const int* c_src   = (const int*)d_in[6];
    const int* c_dst   = (const int*)d_in[7];
    const float* Wk    = (const float*)d_in[8];
    const float* bk    = (const float*)d_in[9];
    const float* Wq    = (const float*)d_in[10];
    const float* bq    = (const float*)d_in[11];
    const float* Wv    = (const float*)d_in[12];
    const float* bv    = (const float*)d_in[13];
    const float* Wfc   = (const float*)d_in[14];
    const float* bfc   = (const float*)d_in[15];
    const float* ln_g  = (const float*)d_in[16];
    const float* ln_b  = (const float*)d_in[17];
    const float* att_w = (const float*)d_in[18];
    const float* val_w = (const float*)d_in[19];
    const float* canon = (const float*)d_in[20];
    const float* res   = (const float*)d_in[21];

    const int NA = in_sizes[0] / 256;
    const int NP = in_sizes[1] / 256;
    const int E0 = in_sizes[2];
    const int E1 = in_sizes[4];
    const int E2 = in_sizes[6];
    const int Nmax = NA > NP ? NA : NP;
    int Emax = E0 > E1 ? E0 : E1; if (E2 > Emax) Emax = E2;

    // workspace layout
    char* p = (char*)d_ws;
    auto alloc = [&](size_t bytes) -> char* {
        char* r = p;
        p += (bytes + 255) & ~(size_t)255;
        return r;
    };
    float* eff_w = (float*)alloc((size_t)6 * 65536 * 4);
    float* eff_b = (float*)alloc(6 * 256 * 4);
    unsigned short* wt = (unsigned short*)alloc((size_t)10 * 65536 * 2); // 0-5 effT, 6-7 WqT, 8-9 WfcT
    unsigned short* ha_bf = (unsigned short*)alloc((size_t)NA * 256 * 2);
    unsigned short* hp_bf = (unsigned short*)alloc((size_t)NP * 256 * 2);
    unsigned short* qa  = (unsigned short*)alloc((size_t)NA * 256 * 2);
    unsigned short* qp  = (unsigned short*)alloc((size_t)NP * 256 * 2);
    unsigned short* keb = (unsigned short*)alloc((size_t)Nmax * 256 * 2);
    unsigned short* veb = (unsigned short*)alloc((size_t)Nmax * 256 * 2);
    unsigned short* agg_w  = (unsigned short*)alloc((size_t)NP * 256 * 2);  // t_paper
    unsigned short* agg_wb = (unsigned short*)alloc((size_t)NA * 256 * 2);  // t_author
    int* cnt    = (int*)alloc((size_t)Nmax * 4);
    int* offs   = (int*)alloc((size_t)Nmax * 4);
    int* cursor = (int*)alloc((size_t)Nmax * 4);
    int* blksum = (int*)alloc(512 * 4);
    int* ssrc   = (int*)alloc((size_t)Emax * 4);

    const float rsdk = 0.17677669529663687f;  // 1/sqrt(32)

    // ---- prep: fused weights, transposed bf16 weights, bf16 features ----
    build_eff<<<dim3(6 * 256), 256, 0, stream>>>(Wk, Wv, att_w, val_w, eff_w);
    build_eff_bias<<<6, 256, 0, stream>>>(bk, bv, att_w, val_w, eff_b);
    for (int m = 0; m < 6; ++m)
        transpose_cast_bf16<<<64, 256, 0, stream>>>(eff_w + (size_t)m * 65536, wt + (size_t)m * 65536);
    transpose_cast_bf16<<<64, 256, 0, stream>>>(Wq,          wt + (size_t)6 * 65536);
    transpose_cast_bf16<<<64, 256, 0, stream>>>(Wq + 65536,  wt + (size_t)7 * 65536);
    transpose_cast_bf16<<<64, 256, 0, stream>>>(Wfc,         wt + (size_t)8 * 65536);
    transpose_cast_bf16<<<64, 256, 0, stream>>>(Wfc + 65536, wt + (size_t)9 * 65536);
    cast_bf16<<<(NA * 64 + 255) / 256, 256, 0, stream>>>(h_a, ha_bf, NA * 64);
    cast_bf16<<<(NP * 64 + 255) / 256, 256, 0, stream>>>(h_p, hp_bf, NP * 64);

    int gA = (NA + 127) / 128, gP = (NP + 127) / 128;

    // q projections
    mfma_gemm<unsigned short><<<gA, 512, 0, stream>>>(ha_bf, wt + (size_t)6 * 65536, bq,        qa, NA);
    mfma_gemm<unsigned short><<<gP, 512, 0, stream>>>(hp_bf, wt + (size_t)7 * 65536, bq + 256,  qp, NP);

    auto run_etype = [&](const int* esrc, const int* edst, int E, int Nd,
                         const unsigned short* qn, const float* canon_e,
                         const unsigned short* other, unsigned short* out) {
        hipMemsetAsync(cnt, 0, (size_t)Nd * 4, stream);
        int gE = (E + 255) / 256, gN = (Nd + 255) / 256;
        k_hist<<<gE, 256, 0, stream>>>(edst, E, cnt);
        k_scan1<<<gN, 256, 0, stream>>>(cnt, offs, blksum, Nd);
        k_scan2<<<1, 512, 0, stream>>>(blksum, gN);
        k_scan3<<<gN, 256, 0, stream>>>(offs, cursor, blksum, Nd);
        k_scatter<<<gE, 256, 0, stream>>>(esrc, edst, E, cursor, ssrc);
        csr_agg<<<(Nd + 3) / 4, 256, 0, stream>>>(offs, cnt, ssrc, qn, keb, veb,
                                                  canon_e, rsdk, other, out, Nd);
    };

    // etype 0: writes (author -> paper), q = q_p
    mfma_gemm<unsigned short><<<gA, 512, 0, stream>>>(ha_bf, wt,                     eff_b,       keb, NA);
    mfma_gemm<unsigned short><<<gA, 512, 0, stream>>>(ha_bf, wt + (size_t)1 * 65536, eff_b + 256, veb, NA);
    run_etype(w_src, w_dst, E0, NP, qp, canon, nullptr, agg_w);

    // etype 1: written-by (paper -> author), q = q_a
    mfma_gemm<unsigned short><<<gP, 512, 0, stream>>>(hp_bf, wt + (size_t)2 * 65536, eff_b + 512, keb, NP);
    mfma_gemm<unsigned short><<<gP, 512, 0, stream>>>(hp_bf, wt + (size_t)3 * 65536, eff_b + 768, veb, NP);
    run_etype(wb_src, wb_dst, E1, NA, qa, canon + 8, nullptr, agg_wb);

    // etype 2: cites (paper -> paper), q = q_p; fuse cross-etype mean with etype0
    mfma_gemm<unsigned short><<<gP, 512, 0, stream>>>(hp_bf, wt + (size_t)4 * 65536, eff_b + 1024, keb, NP);
    mfma_gemm<unsigned short><<<gP, 512, 0, stream>>>(hp_bf, wt + (size_t)5 * 65536, eff_b + 1280, veb, NP);
    run_etype(c_src, c_dst, E2, NP, qp, canon + 16, agg_w, agg_w);

    // output GEMMs (f32 out); alias freed bf16 buffers as f32 scratch
    float* pre_a = (float*)keb;  // keb+veb: 2*Nmax*256*2 bytes >= NA*256*4
    float* pre_p = (float*)qa;   // qa+qp:   (NA+NP)*256*2 bytes >= NP*256*4
    mfma_gemm<float><<<gA, 512, 0, stream>>>(agg_wb, wt + (size_t)8 * 65536, nullptr, pre_a, NA);
    mfma_gemm<float><<<gP, 512, 0, stream>>>(agg_w,  wt + (size_t)9 * 65536, nullptr, pre_p, NP);

    // residual gate + LayerNorm
    finalize_ln<<<(NA + 3) / 4, 256, 0, stream>>>(pre_a, h_a, bfc, ln_g, ln_b, res, 0,
                                                  (float*)d_out, NA);
    finalize_ln<<<(NP + 3) / 4, 256, 0, stream>>>(pre_p, h_p, bfc + 256, ln_g + 256, ln_b + 256, res, 1,
                                                  (float*)d_out + (size_t)NA * 256, NP);
}

// Round 6
// 970.615 us; speedup vs baseline: 6.3157x; 1.1298x over previous
//
#include <hip/hip_runtime.h>
#include <hip/hip_bf16.h>
#include <math.h>

using short8 = __attribute__((ext_vector_type(8))) short;
using f32x4  = __attribute__((ext_vector_type(4))) float;

// ---------- helpers ----------
__device__ __forceinline__ float bf2f(unsigned short u) {
    return __uint_as_float(((unsigned int)u) << 16);
}
__device__ __forceinline__ unsigned short f2bf(float f) {
    unsigned int x = __float_as_uint(f);
    return (unsigned short)((x + 0x7fffu + ((x >> 16) & 1u)) >> 16);
}
// async global->LDS, 16B per lane; LDS dest is wave-uniform base + lane*16
__device__ __forceinline__ void gll16(const void* g, void* l) {
    __builtin_amdgcn_global_load_lds(
        (const __attribute__((address_space(1))) unsigned int*)g,
        (__attribute__((address_space(3))) unsigned int*)l, 16, 0, 0);
}

// ---------- build fused per-edge-type projection weights (f32, [k][n]) ----------
__global__ __launch_bounds__(256) void build_eff(
    const float* __restrict__ Wk, const float* __restrict__ Wv,
    const float* __restrict__ att_w, const float* __restrict__ val_w,
    float* __restrict__ eff)
{
    int gid = blockIdx.x;          // 0 .. 6*256-1
    int mat = gid >> 8;            // 0..5 : e*2 + (0=k,1=v)
    int k = gid & 255;
    int e = mat >> 1, which = mat & 1;
    int ts = (e == 0) ? 0 : 1;
    int c = threadIdx.x;           // 0..255
    int h = c >> 5, j = c & 31;
    const float* Wsrc = (which == 0 ? Wk : Wv) + ((size_t)ts * 256 + k) * 256 + h * 32;
    const float* aw = (which == 0 ? att_w : val_w) + (size_t)((e * 8 + h) * 32) * 32 + j;
    float s = 0.f;
    #pragma unroll
    for (int d = 0; d < 32; ++d) s += Wsrc[d] * aw[d * 32];
    eff[((size_t)mat * 256 + k) * 256 + c] = s;
}

__global__ void build_eff_bias(
    const float* __restrict__ bk, const float* __restrict__ bv,
    const float* __restrict__ att_w, const float* __restrict__ val_w,
    float* __restrict__ effb)
{
    int mat = blockIdx.x;          // 0..5
    int c = threadIdx.x;           // 0..255
    int e = mat >> 1, which = mat & 1;
    int ts = (e == 0) ? 0 : 1;
    int h = c >> 5, j = c & 31;
    const float* bsrc = (which == 0 ? bk : bv) + ts * 256 + h * 32;
    const float* aw = (which == 0 ? att_w : val_w) + (size_t)((e * 8 + h) * 32) * 32 + j;
    float s = 0.f;
    #pragma unroll
    for (int d = 0; d < 32; ++d) s += bsrc[d] * aw[d * 32];
    effb[mat * 256 + c] = s;
}

// ---------- concatenated bias vector [2048] for G1/G2/G3 ----------
__global__ void build_bias_cat(const float* __restrict__ bq,
                               const float* __restrict__ effb,
                               float* __restrict__ bc)
{
    int i = blockIdx.x * 256 + threadIdx.x;   // 0..2047
    int seg = i >> 8, o = i & 255;
    float v;
    switch (seg) {
        case 0: v = bq[o]; break;            // G1: bq author
        case 1: v = effb[o]; break;          // e0 k
        case 2: v = effb[256 + o]; break;    // e0 v
        case 3: v = bq[256 + o]; break;      // G2: bq paper
        case 4: v = effb[512 + o]; break;    // e1 k
        case 5: v = effb[768 + o]; break;    // e1 v
        case 6: v = effb[1024 + o]; break;   // G3: e2 k
        default: v = effb[1280 + o]; break;  // e2 v
    }
    bc[i] = v;
}

// ---------- transpose + cast 10 weight mats into wt_cat [2560][256] bf16 ----------
// mat order: Wq0, e0k, e0v, Wq1, e1k, e1v, e2k, e2v, Wfc0, Wfc1
__global__ __launch_bounds__(256) void transpose_cast_multi(
    const float* __restrict__ Wq, const float* __restrict__ Wfc,
    const float* __restrict__ eff, unsigned short* __restrict__ wt)
{
    __shared__ float tile[32][33];
    int mi = blockIdx.x >> 6;
    int bid = blockIdx.x & 63;
    const float* src;
    switch (mi) {
        case 0: src = Wq; break;
        case 1: src = eff; break;
        case 2: src = eff + 65536; break;
        case 3: src = Wq + 65536; break;
        case 4: src = eff + 2 * 65536; break;
        case 5: src = eff + 3 * 65536; break;
        case 6: src = eff + 4 * 65536; break;
        case 7: src = eff + 5 * 65536; break;
        case 8: src = Wfc; break;
        default: src = Wfc + 65536; break;
    }
    unsigned short* dst = wt + (size_t)mi * 65536;
    int bx = bid & 7, by = bid >> 3;
    int tx = threadIdx.x & 31, ty = threadIdx.x >> 5;
    #pragma unroll
    for (int i = 0; i < 4; ++i)
        tile[ty + i * 8][tx] = src[(size_t)(by * 32 + ty + i * 8) * 256 + bx * 32 + tx];
    __syncthreads();
    #pragma unroll
    for (int i = 0; i < 4; ++i)
        dst[(size_t)(bx * 32 + ty + i * 8) * 256 + by * 32 + tx] = f2bf(tile[tx][ty + i * 8]);
}

// ---------- f32 -> bf16 elementwise cast ----------
__global__ void cast_bf16(const float* __restrict__ in, unsigned short* __restrict__ out, int n4) {
    int i = blockIdx.x * 256 + threadIdx.x;
    if (i < n4) {
        float4 v = ((const float4*)in)[i];
        ushort4 o; o.x = f2bf(v.x); o.y = f2bf(v.y); o.z = f2bf(v.z); o.w = f2bf(v.w);
        ((ushort4*)out)[i] = o;
    }
}

// ======================================================================
// Input-side GEMM: C[M][Ncat] = A[M][256](bf16) @ Wt_seg[Ncat][256]^T + bias
// 256 thr / 4 waves, tile 128x128, BK=32, double-buffered LDS staged via
// global_load_lds(16B). Bank swizzle: granule ^= (row>>1)&3, applied to the
// gll GLOBAL source and the ds_read address (LDS dest stays linear).
// ======================================================================
__global__ __launch_bounds__(256, 4) void gemm_cat(
    const unsigned short* __restrict__ A, const unsigned short* __restrict__ Wt,
    const float* __restrict__ bias, unsigned short* __restrict__ C,
    int M, int Ncat)
{
    __shared__ unsigned short As[2][128 * 32];
    __shared__ unsigned short Bs[2][128 * 32];
    int t = threadIdx.x, w = t >> 6, l = t & 63;
    int lr = l & 15, lg = l >> 4;
    int wr = w >> 1, wc = w & 1;
    int m0 = blockIdx.x * 128, n0 = blockIdx.y * 128;

    // staging lane mapping: issue j covers tile rows j*16..j*16+15
    int lrow = l >> 2, lq = l & 3;
    int qsw = lq ^ ((lrow >> 1) & 3);          // logical k-granule this lane fetches
    int ar0 = m0 + w * 16 + lrow;        if (ar0 >= M) ar0 = M - 1;
    int ar1 = m0 + (w + 4) * 16 + lrow;  if (ar1 >= M) ar1 = M - 1;
    const unsigned short* Ap0 = A + (size_t)ar0 * 256 + qsw * 8;
    const unsigned short* Ap1 = A + (size_t)ar1 * 256 + qsw * 8;
    const unsigned short* Bp0 = Wt + (size_t)(n0 + w * 16 + lrow) * 256 + qsw * 8;
    const unsigned short* Bp1 = Wt + (size_t)(n0 + (w + 4) * 16 + lrow) * 256 + qsw * 8;

    int aswz = (lg ^ ((lr >> 1) & 3)) * 8;     // swizzled read granule (elems)

    f32x4 acc[4][4] = {};

    // prologue: stage k0=0 into buf 0
    gll16(Ap0, &As[0][(w * 16) * 32]);
    gll16(Ap1, &As[0][((w + 4) * 16) * 32]);
    gll16(Bp0, &Bs[0][(w * 16) * 32]);
    gll16(Bp1, &Bs[0][((w + 4) * 16) * 32]);
    __syncthreads();

    int cur = 0;
    for (int step = 0; step < 8; ++step) {
        if (step < 7) {
            int k0 = (step + 1) * 32;
            gll16(Ap0 + k0, &As[cur ^ 1][(w * 16) * 32]);
            gll16(Ap1 + k0, &As[cur ^ 1][((w + 4) * 16) * 32]);
            gll16(Bp0 + k0, &Bs[cur ^ 1][(w * 16) * 32]);
            gll16(Bp1 + k0, &Bs[cur ^ 1][((w + 4) * 16) * 32]);
        }
        short8 fa[4], fb[4];
        #pragma unroll
        for (int f = 0; f < 4; ++f) {
            fa[f] = *(const short8*)&As[cur][(wr * 64 + f * 16 + lr) * 32 + aswz];
            fb[f] = *(const short8*)&Bs[cur][(wc * 64 + f * 16 + lr) * 32 + aswz];
        }
        #pragma unroll
        for (int fr = 0; fr < 4; ++fr)
            #pragma unroll
            for (int fc = 0; fc < 4; ++fc)
                acc[fr][fc] = __builtin_amdgcn_mfma_f32_16x16x32_bf16(fa[fr], fb[fc], acc[fr][fc], 0, 0, 0);
        __syncthreads();
        cur ^= 1;
    }

    // epilogue: C/D map col=lr, row=lg*4+ri
    #pragma unroll
    for (int fr = 0; fr < 4; ++fr) {
        int row = m0 + wr * 64 + fr * 16 + lg * 4;
        #pragma unroll
        for (int fc = 0; fc < 4; ++fc) {
            int col = n0 + wc * 64 + fc * 16 + lr;
            float bv = bias[col];
            #pragma unroll
            for (int ri = 0; ri < 4; ++ri) {
                if (row + ri < M)
                    C[(size_t)(row + ri) * Ncat + col] = f2bf(acc[fr][fc][ri] + bv);
            }
        }
    }
}

// ======================================================================
// Output GEMM + residual gate + LayerNorm fused:
// out[M][256] = LN( alpha*(A@Wfc + bfc) + (1-alpha)*h )
// 512 thr / 8 waves, tile 128x256 (full rows in block), BK=32, dbuf gll.
// ======================================================================
__global__ __launch_bounds__(512, 2) void gemm_ln(
    const unsigned short* __restrict__ A, const unsigned short* __restrict__ Wt,
    const float* __restrict__ hin, const float* __restrict__ bfc,
    const float* __restrict__ g, const float* __restrict__ b,
    const float* __restrict__ res, int nid,
    float* __restrict__ out, int M)
{
    __shared__ unsigned short As[2][128 * 32];
    __shared__ unsigned short Bs[2][256 * 32];
    __shared__ float red_s[128][2], red_q[128][2];
    int t = threadIdx.x, w = t >> 6, l = t & 63;
    int lr = l & 15, lg = l >> 4;
    int wr = w >> 1, wc = w & 1;      // 4 row-groups x 2 col-halves
    int m0 = blockIdx.x * 128;

    int lrow = l >> 2, lq = l & 3;
    int qsw = lq ^ ((lrow >> 1) & 3);
    int ar = m0 + w * 16 + lrow; if (ar >= M) ar = M - 1;
    const unsigned short* Ap  = A  + (size_t)ar * 256 + qsw * 8;
    const unsigned short* Bp0 = Wt + (size_t)(w * 16 + lrow) * 256 + qsw * 8;
    const unsigned short* Bp1 = Wt + (size_t)((w + 8) * 16 + lrow) * 256 + qsw * 8;

    int aswz = (lg ^ ((lr >> 1) & 3)) * 8;

    f32x4 acc[2][8] = {};

    gll16(Ap,  &As[0][(w * 16) * 32]);
    gll16(Bp0, &Bs[0][(w * 16) * 32]);
    gll16(Bp1, &Bs[0][((w + 8) * 16) * 32]);
    __syncthreads();

    int cur = 0;
    for (int step = 0; step < 8; ++step) {
        if (step < 7) {
            int k0 = (step + 1) * 32;
            gll16(Ap + k0,  &As[cur ^ 1][(w * 16) * 32]);
            gll16(Bp0 + k0, &Bs[cur ^ 1][(w * 16) * 32]);
            gll16(Bp1 + k0, &Bs[cur ^ 1][((w + 8) * 16) * 32]);
        }
        short8 fa[2], fb[8];
        #pragma unroll
        for (int f = 0; f < 2; ++f)
            fa[f] = *(const short8*)&As[cur][(wr * 32 + f * 16 + lr) * 32 + aswz];
        #pragma unroll
        for (int f = 0; f < 8; ++f)
            fb[f] = *(const short8*)&Bs[cur][(wc * 128 + f * 16 + lr) * 32 + aswz];
        #pragma unroll
        for (int fr = 0; fr < 2; ++fr)
            #pragma unroll
            for (int fc = 0; fc < 8; ++fc)
                acc[fr][fc] = __builtin_amdgcn_mfma_f32_16x16x32_bf16(fa[fr], fb[fc], acc[fr][fc], 0, 0, 0);
        __syncthreads();
        cur ^= 1;
    }

    float alpha = 1.f / (1.f + __expf(-res[nid]));
    float beta = 1.f - alpha;

    // gate + partial row sums (rows: wr*32 + fr*16 + lg*4 + ri; cols: wc*128 + fc*16 + lr)
    #pragma unroll
    for (int fr = 0; fr < 2; ++fr) {
        #pragma unroll
        for (int ri = 0; ri < 4; ++ri) {
            int rloc = wr * 32 + fr * 16 + lg * 4 + ri;
            int row = m0 + rloc;
            int rowc = row < M ? row : M - 1;
            float ps = 0.f, pq = 0.f;
            #pragma unroll
            for (int fc = 0; fc < 8; ++fc) {
                int col = wc * 128 + fc * 16 + lr;
                float hp = alpha * (acc[fr][fc][ri] + bfc[col])
                         + beta * hin[(size_t)rowc * 256 + col];
                acc[fr][fc][ri] = hp;
                ps += hp;
                pq += hp * hp;
            }
            #pragma unroll
            for (int m = 1; m < 16; m <<= 1) {
                ps += __shfl_xor(ps, m);
                pq += __shfl_xor(pq, m);
            }
            if (lr == 0) { red_s[rloc][wc] = ps; red_q[rloc][wc] = pq; }
        }
    }
    __syncthreads();
    #pragma unroll
    for (int fr = 0; fr < 2; ++fr) {
        #pragma unroll
        for (int ri = 0; ri < 4; ++ri) {
            int rloc = wr * 32 + fr * 16 + lg * 4 + ri;
            int row = m0 + rloc;
            float s = red_s[rloc][0] + red_s[rloc][1];
            float q = red_q[rloc][0] + red_q[rloc][1];
            float mu = s * (1.f / 256.f);
            float var = q * (1.f / 256.f) - mu * mu;
            float rstd = rsqrtf(var + 1e-5f);
            if (row < M) {
                #pragma unroll
                for (int fc = 0; fc < 8; ++fc) {
                    int col = wc * 128 + fc * 16 + lr;
                    out[(size_t)row * 256 + col] =
                        (acc[fr][fc][ri] - mu) * rstd * g[col] + b[col];
                }
            }
        }
    }
}

// ---------- CSR build: histogram + scan + scatter ----------
__global__ void k_hist(const int* __restrict__ dst, int E, int* __restrict__ cnt) {
    int e = blockIdx.x * 256 + threadIdx.x;
    if (e < E) atomicAdd(&cnt[dst[e]], 1);
}

__global__ __launch_bounds__(256) void k_scan1(
    const int* __restrict__ cnt, int* __restrict__ offs, int* __restrict__ blksum, int N)
{
    __shared__ int sm[256];
    int t = threadIdx.x, i = blockIdx.x * 256 + t;
    int x = (i < N) ? cnt[i] : 0;
    sm[t] = x; __syncthreads();
    int v = x;
    #pragma unroll
    for (int off = 1; off < 256; off <<= 1) {
        int y = (t >= off) ? sm[t - off] : 0;
        __syncthreads();
        v += y; sm[t] = v;
        __syncthreads();
    }
    if (i < N) offs[i] = v - x;
    if (t == 255) blksum[blockIdx.x] = v;
}

__global__ __launch_bounds__(512) void k_scan2(int* __restrict__ blksum, int nb) {
    __shared__ int sm[512];
    int t = threadIdx.x;
    int x = (t < nb) ? blksum[t] : 0;
    sm[t] = x; __syncthreads();
    int v = x;
    #pragma unroll
    for (int off = 1; off < 512; off <<= 1) {
        int y = (t >= off) ? sm[t - off] : 0;
        __syncthreads();
        v += y; sm[t] = v;
        __syncthreads();
    }
    if (t < nb) blksum[t] = v - x;
}

__global__ void k_scan3(int* __restrict__ offs, int* __restrict__ cursor,
                        const int* __restrict__ blksum, int N)
{
    int i = blockIdx.x * 256 + threadIdx.x;
    if (i < N) {
        int v = offs[i] + blksum[i >> 8];
        offs[i] = v;
        cursor[i] = v;
    }
}

__global__ void k_scatter(const int* __restrict__ src, const int* __restrict__ dst, int E,
                          int* __restrict__ cursor, int* __restrict__ ssrc)
{
    int e = blockIdx.x * 256 + threadIdx.x;
    if (e < E) {
        int pos = atomicAdd(&cursor[dst[e]], 1);
        ssrc[pos] = src[e];
    }
}

// ---------- CSR aggregation: one wave per destination node ----------
// q/ke/ve are column slices of packed buffers; strides in elements.
__global__ __launch_bounds__(256) void csr_agg(
    const int* __restrict__ offs, const int* __restrict__ cnt,
    const int* __restrict__ ssrc,
    const unsigned short* __restrict__ q,  int qs,
    const unsigned short* __restrict__ ke, int ks,
    const unsigned short* __restrict__ ve, int vs,
    const float* __restrict__ canon,
    float rsdk,
    const unsigned short* __restrict__ other,
    unsigned short* __restrict__ out, int N)
{
    int wave = threadIdx.x >> 6, lane = threadIdx.x & 63;
    int n = blockIdx.x * 4 + wave;
    if (n >= N) return;
    ushort4 qv = *(const ushort4*)(q + (size_t)n * qs + lane * 4);
    float q0 = bf2f(qv.x), q1 = bf2f(qv.y), q2 = bf2f(qv.z), q3 = bf2f(qv.w);
    int base = offs[n], deg = cnt[n];
    int h = lane >> 3;
    float cw = canon[h] * rsdk;
    float den = 0.f, a0 = 0.f, a1 = 0.f, a2 = 0.f, a3 = 0.f;
    for (int i = 0; i < deg; ++i) {
        int s = ssrc[base + i];
        ushort4 kv = *(const ushort4*)(ke + (size_t)s * ks + lane * 4);
        float p = q0 * bf2f(kv.x) + q1 * bf2f(kv.y) + q2 * bf2f(kv.z) + q3 * bf2f(kv.w);
        p += __shfl_xor(p, 1);
        p += __shfl_xor(p, 2);
        p += __shfl_xor(p, 4);
        float ex = __expf(p * cw);
        ushort4 vv = *(const ushort4*)(ve + (size_t)s * vs + lane * 4);
        den += ex;
        a0 += ex * bf2f(vv.x);
        a1 += ex * bf2f(vv.y);
        a2 += ex * bf2f(vv.z);
        a3 += ex * bf2f(vv.w);
    }
    float r = den > 0.f ? 1.f / den : 0.f;
    a0 *= r; a1 *= r; a2 *= r; a3 *= r;
    if (other) {
        ushort4 ov = ((const ushort4*)(other + (size_t)n * 256))[lane];
        a0 = 0.5f * (a0 + bf2f(ov.x));
        a1 = 0.5f * (a1 + bf2f(ov.y));
        a2 = 0.5f * (a2 + bf2f(ov.z));
        a3 = 0.5f * (a3 + bf2f(ov.w));
    }
    ushort4 o4; o4.x = f2bf(a0); o4.y = f2bf(a1); o4.z = f2bf(a2); o4.w = f2bf(a3);
    ((ushort4*)(out + (size_t)n * 256))[lane] = o4;
}

// ---------- launch ----------
extern "C" void kernel_launch(void* const* d_in, const int* in_sizes, int n_in,
                              void* d_out, int out_size, void* d_ws, size_t ws_size,
                              hipStream_t stream)
{
    const float* h_a   = (const float*)d_in[0];
    const float* h_p   = (const float*)d_in[1];
    const int* w_src   = (const int*)d_in[2];
    const int* w_dst   = (const int*)d_in[3];
    const int* wb_src  = (const int*)d_in[4];
    const int* wb_dst  = (const int*)d_in[5];
    const int* c_src   = (const int*)d_in[6];
    const int* c_dst   = (const int*)d_in[7];
    const float* Wk    = (const float*)d_in[8];
    const float* bk    = (const float*)d_in[9];
    const float* Wq    = (const float*)d_in[10];
    const float* bq    = (const float*)d_in[11];
    const float* Wv    = (const float*)d_in[12];
    const float* bv    = (const float*)d_in[13];
    const float* Wfc   = (const float*)d_in[14];
    const float* bfc   = (const float*)d_in[15];
    const float* ln_g  = (const float*)d_in[16];
    const float* ln_b  = (const float*)d_in[17];
    const float* att_w = (const float*)d_in[18];
    const float* val_w = (const float*)d_in[19];
    const float* canon = (const float*)d_in[20];
    const float* res   = (const float*)d_in[21];

    const int NA = in_sizes[0] / 256;
    const int NP = in_sizes[1] / 256;
    const int E0 = in_sizes[2];
    const int E1 = in_sizes[4];
    const int E2 = in_sizes[6];
    const int Nmax = NA > NP ? NA : NP;
    int Emax = E0 > E1 ? E0 : E1; if (E2 > Emax) Emax = E2;

    // workspace layout
    char* p = (char*)d_ws;
    auto alloc = [&](size_t bytes) -> char* {
        char* r = p;
        p += (bytes + 255) & ~(size_t)255;
        return r;
    };
    float* eff_w = (float*)alloc((size_t)6 * 65536 * 4);
    float* eff_b = (float*)alloc(6 * 256 * 4);
    unsigned short* wt = (unsigned short*)alloc((size_t)10 * 65536 * 2); // 2560 rows x 256
    float* bias_cat = (float*)alloc(2048 * 4);
    unsigned short* qkv_a = (unsigned short*)alloc((size_t)NA * 768 * 2);
    unsigned short* qkv_p = (unsigned short*)alloc((size_t)NP * 768 * 2);
    unsigned short* kv2   = (unsigned short*)alloc((size_t)NP * 512 * 2);
    unsigned short* agg_w  = (unsigned short*)alloc((size_t)NP * 256 * 2);  // t_paper
    unsigned short* agg_wb = (unsigned short*)alloc((size_t)NA * 256 * 2);  // t_author
    int* cnt    = (int*)alloc((size_t)Nmax * 4);
    int* offs   = (int*)alloc((size_t)Nmax * 4);
    int* cursor = (int*)alloc((size_t)Nmax * 4);
    int* blksum = (int*)alloc(512 * 4);
    int* ssrc   = (int*)alloc((size_t)Emax * 4);

    // bf16 feature copies carved from d_out's first half (freed before G4/G5 write)
    unsigned short* ha_bf = (unsigned short*)d_out;
    unsigned short* hp_bf = ha_bf + (size_t)NA * 256;

    const float rsdk = 0.17677669529663687f;  // 1/sqrt(32)

    // ---- prep ----
    build_eff<<<dim3(6 * 256), 256, 0, stream>>>(Wk, Wv, att_w, val_w, eff_w);
    build_eff_bias<<<6, 256, 0, stream>>>(bk, bv, att_w, val_w, eff_b);
    build_bias_cat<<<8, 256, 0, stream>>>(bq, eff_b, bias_cat);
    transpose_cast_multi<<<640, 256, 0, stream>>>(Wq, Wfc, eff_w, wt);
    cast_bf16<<<(NA * 64 + 255) / 256, 256, 0, stream>>>(h_a, ha_bf, NA * 64);
    cast_bf16<<<(NP * 64 + 255) / 256, 256, 0, stream>>>(h_p, hp_bf, NP * 64);

    int gA = (NA + 127) / 128, gP = (NP + 127) / 128;

    // G1: author [q|k0|v0], G2: paper [q|k1|v1]
    gemm_cat<<<dim3(gA, 6), 256, 0, stream>>>(ha_bf, wt,                  bias_cat,        qkv_a, NA, 768);
    gemm_cat<<<dim3(gP, 6), 256, 0, stream>>>(hp_bf, wt + (size_t)768*256, bias_cat + 768,  qkv_p, NP, 768);

    auto run_etype = [&](const int* esrc, const int* edst, int E, int Nd,
                         const unsigned short* qn, int qs,
                         const unsigned short* kee, int ks,
                         const unsigned short* vee, int vs,
                         const float* canon_e,
                         const unsigned short* other, unsigned short* out) {
        hipMemsetAsync(cnt, 0, (size_t)Nd * 4, stream);
        int gE = (E + 255) / 256, gN = (Nd + 255) / 256;
        k_hist<<<gE, 256, 0, stream>>>(edst, E, cnt);
        k_scan1<<<gN, 256, 0, stream>>>(cnt, offs, blksum, Nd);
        k_scan2<<<1, 512, 0, stream>>>(blksum, gN);
        k_scan3<<<gN, 256, 0, stream>>>(offs, cursor, blksum, Nd);
        k_scatter<<<gE, 256, 0, stream>>>(esrc, edst, E, cursor, ssrc);
        csr_agg<<<(Nd + 3) / 4, 256, 0, stream>>>(offs, cnt, ssrc, qn, qs, kee, ks, vee, vs,
                                                  canon_e, rsdk, other, out, Nd);
    };

    // e0: writes (author -> paper): q=qkv_p col0, k/v=qkv_a cols 256/512
    run_etype(w_src, w_dst, E0, NP, qkv_p, 768, qkv_a + 256, 768, qkv_a + 512, 768,
              canon, nullptr, agg_w);
    // e1: written-by (paper -> author): q=qkv_a, k/v=qkv_p
    run_etype(wb_src, wb_dst, E1, NA, qkv_a, 768, qkv_p + 256, 768, qkv_p + 512, 768,
              canon + 8, nullptr, agg_wb);
    // G3: paper [k2|v2]
    gemm_cat<<<dim3(gP, 4), 256, 0, stream>>>(hp_bf, wt + (size_t)1536*256, bias_cat + 1536, kv2, NP, 512);
    // e2: cites (paper -> paper); fuse cross-etype mean with e0's agg_w
    run_etype(c_src, c_dst, E2, NP, qkv_p, 768, kv2, 512, kv2 + 256, 512,
              canon + 16, agg_w, agg_w);

    // G4/G5: output GEMM + gate + LayerNorm fused, writes d_out directly
    gemm_ln<<<gA, 512, 0, stream>>>(agg_wb, wt + (size_t)2048*256, h_a, bfc,
                                    ln_g, ln_b, res, 0, (float*)d_out, NA);
    gemm_ln<<<gP, 512, 0, stream>>>(agg_w,  wt + (size_t)2304*256, h_p, bfc + 256,
                                    ln_g + 256, ln_b + 256, res, 1,
                                    (float*)d_out + (size_t)NA * 256, NP);
}

// Round 7
// 835.311 us; speedup vs baseline: 7.3388x; 1.1620x over previous
//
#include <hip/hip_runtime.h>
#include <hip/hip_bf16.h>
#include <math.h>

using short8  = __attribute__((ext_vector_type(8))) short;
using ushort8v = __attribute__((ext_vector_type(8))) unsigned short;
using f32x4   = __attribute__((ext_vector_type(4))) float;

// ---------- helpers ----------
__device__ __forceinline__ float bf2f(unsigned short u) {
    return __uint_as_float(((unsigned int)u) << 16);
}
__device__ __forceinline__ unsigned short f2bf(float f) {
    unsigned int x = __float_as_uint(f);
    return (unsigned short)((x + 0x7fffu + ((x >> 16) & 1u)) >> 16);
}
// async global->LDS, 16B per lane; LDS dest is wave-uniform base + lane*16
__device__ __forceinline__ void gll16(const void* g, void* l) {
    __builtin_amdgcn_global_load_lds(
        (const __attribute__((address_space(1))) unsigned int*)g,
        (__attribute__((address_space(3))) unsigned int*)l, 16, 0, 0);
}

// ---------- fused per-edge-type projection weights, written transposed bf16 ----------
// wt slots (rows of [2560][256]): 0 Wq0 | 1 e0k | 2 e0v | 3 Wq1 | 4 e1k | 5 e1v
//                                 | 6 e2k | 7 e2v | 8 Wfc0 | 9 Wfc1
__global__ __launch_bounds__(256) void build_eff_t(
    const float* __restrict__ Wk, const float* __restrict__ Wv,
    const float* __restrict__ att_w, const float* __restrict__ val_w,
    unsigned short* __restrict__ wt)
{
    int gid = blockIdx.x;          // mat*256 + c
    int mat = gid >> 8, c = gid & 255;   // mat: e*2 + (0=k,1=v)
    int e = mat >> 1, which = mat & 1;
    int ts = (e == 0) ? 0 : 1;
    int h = c >> 5, j = c & 31;
    int k = threadIdx.x;
    const float* Wsrc = (which == 0 ? Wk : Wv) + ((size_t)ts * 256 + k) * 256 + h * 32;
    const float* aw = (which == 0 ? att_w : val_w) + (size_t)((e * 8 + h) * 32) * 32 + j;
    float s = 0.f;
    #pragma unroll
    for (int d = 0; d < 32; ++d) s += Wsrc[d] * aw[d * 32];
    int slot = mat < 2 ? mat + 1 : mat + 2;
    wt[((size_t)slot * 256 + c) * 256 + k] = f2bf(s);
}

__global__ void build_eff_bias(
    const float* __restrict__ bk, const float* __restrict__ bv,
    const float* __restrict__ att_w, const float* __restrict__ val_w,
    float* __restrict__ effb)
{
    int mat = blockIdx.x;          // 0..5
    int c = threadIdx.x;
    int e = mat >> 1, which = mat & 1;
    int ts = (e == 0) ? 0 : 1;
    int h = c >> 5, j = c & 31;
    const float* bsrc = (which == 0 ? bk : bv) + ts * 256 + h * 32;
    const float* aw = (which == 0 ? att_w : val_w) + (size_t)((e * 8 + h) * 32) * 32 + j;
    float s = 0.f;
    #pragma unroll
    for (int d = 0; d < 32; ++d) s += bsrc[d] * aw[d * 32];
    effb[mat * 256 + c] = s;
}

// bias_cat[2048]: [bq0|e0k|e0v]  [bq1|e1k|e1v|e2k|e2v]
__global__ void build_bias_cat(const float* __restrict__ bq,
                               const float* __restrict__ effb,
                               float* __restrict__ bc)
{
    int i = blockIdx.x * 256 + threadIdx.x;
    int seg = i >> 8, o = i & 255;
    float v;
    switch (seg) {
        case 0: v = bq[o]; break;
        case 1: v = effb[o]; break;
        case 2: v = effb[256 + o]; break;
        case 3: v = bq[256 + o]; break;
        case 4: v = effb[512 + o]; break;
        case 5: v = effb[768 + o]; break;
        case 6: v = effb[1024 + o]; break;
        default: v = effb[1280 + o]; break;
    }
    bc[i] = v;
}

// transpose+cast Wq0, Wq1, Wfc0, Wfc1 into wt slots 0,3,8,9
__global__ __launch_bounds__(256) void transpose_cast4(
    const float* __restrict__ Wq, const float* __restrict__ Wfc,
    unsigned short* __restrict__ wt)
{
    __shared__ float tile[32][33];
    int mi = blockIdx.x >> 6;
    int bid = blockIdx.x & 63;
    const float* src; int slot;
    switch (mi) {
        case 0: src = Wq;           slot = 0; break;
        case 1: src = Wq + 65536;   slot = 3; break;
        case 2: src = Wfc;          slot = 8; break;
        default: src = Wfc + 65536; slot = 9; break;
    }
    unsigned short* dst = wt + (size_t)slot * 65536;
    int bx = bid & 7, by = bid >> 3;
    int tx = threadIdx.x & 31, ty = threadIdx.x >> 5;
    #pragma unroll
    for (int i = 0; i < 4; ++i)
        tile[ty + i * 8][tx] = src[(size_t)(by * 32 + ty + i * 8) * 256 + bx * 32 + tx];
    __syncthreads();
    #pragma unroll
    for (int i = 0; i < 4; ++i)
        dst[(size_t)(bx * 32 + ty + i * 8) * 256 + by * 32 + tx] = f2bf(tile[tx][ty + i * 8]);
}

__global__ void cast_bf16(const float* __restrict__ in, unsigned short* __restrict__ out, int n4) {
    int i = blockIdx.x * 256 + threadIdx.x;
    if (i < n4) {
        float4 v = ((const float4*)in)[i];
        ushort4 o; o.x = f2bf(v.x); o.y = f2bf(v.y); o.z = f2bf(v.z); o.w = f2bf(v.w);
        ((ushort4*)out)[i] = o;
    }
}

// ======================================================================
// Input-side GEMM: C[M][Ncat] = A[M][256](bf16) @ Wt_seg (+bias), tile 128x128,
// 256 thr / 4 waves, BK=32, dbuf global_load_lds(16B), both-sides XOR swizzle.
// ======================================================================
__global__ __launch_bounds__(256, 4) void gemm_cat(
    const unsigned short* __restrict__ A, const unsigned short* __restrict__ Wt,
    const float* __restrict__ bias, unsigned short* __restrict__ C,
    int M, int Ncat)
{
    __shared__ unsigned short As[2][128 * 32];
    __shared__ unsigned short Bs[2][128 * 32];
    int t = threadIdx.x, w = t >> 6, l = t & 63;
    int lr = l & 15, lg = l >> 4;
    int wr = w >> 1, wc = w & 1;
    int m0 = blockIdx.x * 128, n0 = blockIdx.y * 128;

    int lrow = l >> 2, lq = l & 3;
    int qsw = lq ^ ((lrow >> 1) & 3);
    int ar0 = m0 + w * 16 + lrow;        if (ar0 >= M) ar0 = M - 1;
    int ar1 = m0 + (w + 4) * 16 + lrow;  if (ar1 >= M) ar1 = M - 1;
    const unsigned short* Ap0 = A + (size_t)ar0 * 256 + qsw * 8;
    const unsigned short* Ap1 = A + (size_t)ar1 * 256 + qsw * 8;
    const unsigned short* Bp0 = Wt + (size_t)(n0 + w * 16 + lrow) * 256 + qsw * 8;
    const unsigned short* Bp1 = Wt + (size_t)(n0 + (w + 4) * 16 + lrow) * 256 + qsw * 8;

    int aswz = (lg ^ ((lr >> 1) & 3)) * 8;

    f32x4 acc[4][4] = {};

    gll16(Ap0, &As[0][(w * 16) * 32]);
    gll16(Ap1, &As[0][((w + 4) * 16) * 32]);
    gll16(Bp0, &Bs[0][(w * 16) * 32]);
    gll16(Bp1, &Bs[0][((w + 4) * 16) * 32]);
    __syncthreads();

    int cur = 0;
    for (int step = 0; step < 8; ++step) {
        if (step < 7) {
            int k0 = (step + 1) * 32;
            gll16(Ap0 + k0, &As[cur ^ 1][(w * 16) * 32]);
            gll16(Ap1 + k0, &As[cur ^ 1][((w + 4) * 16) * 32]);
            gll16(Bp0 + k0, &Bs[cur ^ 1][(w * 16) * 32]);
            gll16(Bp1 + k0, &Bs[cur ^ 1][((w + 4) * 16) * 32]);
        }
        short8 fa[4], fb[4];
        #pragma unroll
        for (int f = 0; f < 4; ++f) {
            fa[f] = *(const short8*)&As[cur][(wr * 64 + f * 16 + lr) * 32 + aswz];
            fb[f] = *(const short8*)&Bs[cur][(wc * 64 + f * 16 + lr) * 32 + aswz];
        }
        #pragma unroll
        for (int fr = 0; fr < 4; ++fr)
            #pragma unroll
            for (int fc = 0; fc < 4; ++fc)
                acc[fr][fc] = __builtin_amdgcn_mfma_f32_16x16x32_bf16(fa[fr], fb[fc], acc[fr][fc], 0, 0, 0);
        __syncthreads();
        cur ^= 1;
    }

    #pragma unroll
    for (int fr = 0; fr < 4; ++fr) {
        int row = m0 + wr * 64 + fr * 16 + lg * 4;
        #pragma unroll
        for (int fc = 0; fc < 4; ++fc) {
            int col = n0 + wc * 64 + fc * 16 + lr;
            float bv = bias[col];
            #pragma unroll
            for (int ri = 0; ri < 4; ++ri) {
                if (row + ri < M)
                    C[(size_t)(row + ri) * Ncat + col] = f2bf(acc[fr][fc][ri] + bv);
            }
        }
    }
}

// ======================================================================
// Output GEMM + gate + LayerNorm, author and paper batched in one grid.
// ======================================================================
__global__ __launch_bounds__(512, 2) void gemm_ln2(
    const unsigned short* __restrict__ Aa, const unsigned short* __restrict__ Ap2,
    const unsigned short* __restrict__ WtFc,  // 512 rows: [Wfc0T | Wfc1T]
    const float* __restrict__ hA, const float* __restrict__ hP,
    const float* __restrict__ bfc, const float* __restrict__ gg,
    const float* __restrict__ bb, const float* __restrict__ res,
    float* __restrict__ out, int NA, int NP, int nbA)
{
    __shared__ unsigned short As[2][128 * 32];
    __shared__ unsigned short Bs[2][256 * 32];
    __shared__ float red_s[128][2], red_q[128][2];

    int bid = blockIdx.x;
    int isP = bid >= nbA;
    int m0 = (isP ? bid - nbA : bid) * 128;
    int M = isP ? NP : NA;
    const unsigned short* A = isP ? Ap2 : Aa;
    const float* hin = isP ? hP : hA;
    float* o = out + (isP ? (size_t)NA * 256 : 0);
    const unsigned short* Wt = WtFc + (isP ? (size_t)256 * 256 : 0);
    const float* bfcn = bfc + (isP ? 256 : 0);
    const float* gn = gg + (isP ? 256 : 0);
    const float* bn = bb + (isP ? 256 : 0);
    float alpha = 1.f / (1.f + __expf(-res[isP ? 1 : 0]));
    float beta = 1.f - alpha;

    int t = threadIdx.x, w = t >> 6, l = t & 63;
    int lr = l & 15, lg = l >> 4;
    int wr = w >> 1, wc = w & 1;

    int lrow = l >> 2, lq = l & 3;
    int qsw = lq ^ ((lrow >> 1) & 3);
    int ar = m0 + w * 16 + lrow; if (ar >= M) ar = M - 1;
    const unsigned short* Apt = A  + (size_t)ar * 256 + qsw * 8;
    const unsigned short* Bp0 = Wt + (size_t)(w * 16 + lrow) * 256 + qsw * 8;
    const unsigned short* Bp1 = Wt + (size_t)((w + 8) * 16 + lrow) * 256 + qsw * 8;

    int aswz = (lg ^ ((lr >> 1) & 3)) * 8;

    f32x4 acc[2][8] = {};

    gll16(Apt, &As[0][(w * 16) * 32]);
    gll16(Bp0, &Bs[0][(w * 16) * 32]);
    gll16(Bp1, &Bs[0][((w + 8) * 16) * 32]);
    __syncthreads();

    int cur = 0;
    for (int step = 0; step < 8; ++step) {
        if (step < 7) {
            int k0 = (step + 1) * 32;
            gll16(Apt + k0, &As[cur ^ 1][(w * 16) * 32]);
            gll16(Bp0 + k0, &Bs[cur ^ 1][(w * 16) * 32]);
            gll16(Bp1 + k0, &Bs[cur ^ 1][((w + 8) * 16) * 32]);
        }
        short8 fa[2], fb[8];
        #pragma unroll
        for (int f = 0; f < 2; ++f)
            fa[f] = *(const short8*)&As[cur][(wr * 32 + f * 16 + lr) * 32 + aswz];
        #pragma unroll
        for (int f = 0; f < 8; ++f)
            fb[f] = *(const short8*)&Bs[cur][(wc * 128 + f * 16 + lr) * 32 + aswz];
        #pragma unroll
        for (int fr = 0; fr < 2; ++fr)
            #pragma unroll
            for (int fc = 0; fc < 8; ++fc)
                acc[fr][fc] = __builtin_amdgcn_mfma_f32_16x16x32_bf16(fa[fr], fb[fc], acc[fr][fc], 0, 0, 0);
        __syncthreads();
        cur ^= 1;
    }

    #pragma unroll
    for (int fr = 0; fr < 2; ++fr) {
        #pragma unroll
        for (int ri = 0; ri < 4; ++ri) {
            int rloc = wr * 32 + fr * 16 + lg * 4 + ri;
            int row = m0 + rloc;
            int rowc = row < M ? row : M - 1;
            float ps = 0.f, pq = 0.f;
            #pragma unroll
            for (int fc = 0; fc < 8; ++fc) {
                int col = wc * 128 + fc * 16 + lr;
                float hp = alpha * (acc[fr][fc][ri] + bfcn[col])
                         + beta * hin[(size_t)rowc * 256 + col];
                acc[fr][fc][ri] = hp;
                ps += hp;
                pq += hp * hp;
            }
            #pragma unroll
            for (int m = 1; m < 16; m <<= 1) {
                ps += __shfl_xor(ps, m);
                pq += __shfl_xor(pq, m);
            }
            if (lr == 0) { red_s[rloc][wc] = ps; red_q[rloc][wc] = pq; }
        }
    }
    __syncthreads();
    #pragma unroll
    for (int fr = 0; fr < 2; ++fr) {
        #pragma unroll
        for (int ri = 0; ri < 4; ++ri) {
            int rloc = wr * 32 + fr * 16 + lg * 4 + ri;
            int row = m0 + rloc;
            float s = red_s[rloc][0] + red_s[rloc][1];
            float q = red_q[rloc][0] + red_q[rloc][1];
            float mu = s * (1.f / 256.f);
            float var = q * (1.f / 256.f) - mu * mu;
            float rstd = rsqrtf(var + 1e-5f);
            if (row < M) {
                #pragma unroll
                for (int fc = 0; fc < 8; ++fc) {
                    int col = wc * 128 + fc * 16 + lr;
                    o[(size_t)row * 256 + col] =
                        (acc[fr][fc][ri] - mu) * rstd * gn[col] + bn[col];
                }
            }
        }
    }
}

// ---------- batched CSR build over 3 edge lists ----------
__global__ void k_hist3(const int* __restrict__ d0, const int* __restrict__ d1,
                        const int* __restrict__ d2, int E0, int E1, int E2,
                        int nb0, int nb01, int P, int* __restrict__ cnt)
{
    int bid = blockIdx.x;
    const int* d; int E, eb, base;
    if (bid < nb0)       { d = d0; E = E0; eb = bid;        base = 0; }
    else if (bid < nb01) { d = d1; E = E1; eb = bid - nb0;  base = P; }
    else                 { d = d2; E = E2; eb = bid - nb01; base = 2 * P; }
    int e = eb * 256 + threadIdx.x;
    if (e < E) atomicAdd(&cnt[base + d[e]], 1);
}

__global__ __launch_bounds__(256) void k_scan1(
    const int* __restrict__ cnt, int* __restrict__ offs, int* __restrict__ blksum, int N)
{
    __shared__ int sm[256];
    int t = threadIdx.x, i = blockIdx.x * 256 + t;
    int x = (i < N) ? cnt[i] : 0;
    sm[t] = x; __syncthreads();
    int v = x;
    #pragma unroll
    for (int off = 1; off < 256; off <<= 1) {
        int y = (t >= off) ? sm[t - off] : 0;
        __syncthreads();
        v += y; sm[t] = v;
        __syncthreads();
    }
    if (i < N) offs[i] = v - x;
    if (t == 255) blksum[blockIdx.x] = v;
}

// per-segment exclusive scan of block sums (3 segments of nbseg entries)
__global__ __launch_bounds__(512) void k_scan2s(int* __restrict__ blksum, int nbseg) {
    __shared__ int sm[512];
    int t = threadIdx.x;
    int* bs = blksum + blockIdx.x * nbseg;
    int x = (t < nbseg) ? bs[t] : 0;
    sm[t] = x; __syncthreads();
    int v = x;
    #pragma unroll
    for (int off = 1; off < 512; off <<= 1) {
        int y = (t >= off) ? sm[t - off] : 0;
        __syncthreads();
        v += y; sm[t] = v;
        __syncthreads();
    }
    if (t < nbseg) bs[t] = v - x;
}

__global__ void k_scan3(int* __restrict__ offs, int* __restrict__ cursor,
                        const int* __restrict__ blksum, int N)
{
    int i = blockIdx.x * 256 + threadIdx.x;
    if (i < N) {
        int v = offs[i] + blksum[i >> 8];
        offs[i] = v;
        cursor[i] = v;
    }
}

__global__ void k_scatter3(const int* __restrict__ s0, const int* __restrict__ d0,
                           const int* __restrict__ s1, const int* __restrict__ d1,
                           const int* __restrict__ s2, const int* __restrict__ d2,
                           int E0, int E1, int E2, int nb0, int nb01, int P,
                           int* __restrict__ cursor, int* __restrict__ ssrc)
{
    int bid = blockIdx.x;
    const int* s; const int* d; int E, eb, bn, be;
    if (bid < nb0)       { s = s0; d = d0; E = E0; eb = bid;        bn = 0;     be = 0; }
    else if (bid < nb01) { s = s1; d = d1; E = E1; eb = bid - nb0;  bn = P;     be = E0; }
    else                 { s = s2; d = d2; E = E2; eb = bid - nb01; bn = 2 * P; be = E0 + E1; }
    int e = eb * 256 + threadIdx.x;
    if (e < E) {
        int pos = atomicAdd(&cursor[bn + d[e]], 1);
        ssrc[be + pos] = s[e];
    }
}

// ---------- segment softmax-aggregate: 2 edges/iteration, 16B loads ----------
__device__ __forceinline__ void seg_agg8(
    int base, int deg, const int* __restrict__ ssrc,
    const unsigned short* __restrict__ ke, int ks,
    const unsigned short* __restrict__ ve, int vs,
    const float* qf, float cw, int sl, int half,
    float* o)
{
    float den = 0.f;
    float acc[8] = {0.f,0.f,0.f,0.f,0.f,0.f,0.f,0.f};
    for (int i = 0; i < deg; i += 2) {
        int idx = i + half;
        if (idx < deg) {
            int s = ssrc[base + idx];
            ushort8v kv = *(const ushort8v*)(ke + (size_t)s * ks + sl * 8);
            float p = qf[0] * bf2f(kv[0]) + qf[1] * bf2f(kv[1])
                    + qf[2] * bf2f(kv[2]) + qf[3] * bf2f(kv[3])
                    + qf[4] * bf2f(kv[4]) + qf[5] * bf2f(kv[5])
                    + qf[6] * bf2f(kv[6]) + qf[7] * bf2f(kv[7]);
            p += __shfl_xor(p, 1);
            p += __shfl_xor(p, 2);
            float ex = __expf(p * cw);
            ushort8v vv = *(const ushort8v*)(ve + (size_t)s * vs + sl * 8);
            den += ex;
            #pragma unroll
            for (int j = 0; j < 8; ++j) acc[j] += ex * bf2f(vv[j]);
        }
    }
    den += __shfl_xor(den, 32);
    #pragma unroll
    for (int j = 0; j < 8; ++j) acc[j] += __shfl_xor(acc[j], 32);
    float r = den > 0.f ? 1.f / den : 0.f;
    #pragma unroll
    for (int j = 0; j < 8; ++j) o[j] = acc[j] * r;
}

// ---------- all three edge-type aggregations in one dispatch ----------
// nodes [0,NP): papers (e0 writes + e2 cites, 0.5*mean) ; [NP,NP+NA): authors (e1)
__global__ __launch_bounds__(256) void agg_all(
    const int* __restrict__ cnt, const int* __restrict__ offs,
    const int* __restrict__ ssrc, int P, int E0, int E1,
    const unsigned short* __restrict__ qkv_a,   // [NA][768]  q|k0|v0
    const unsigned short* __restrict__ qkv_p,   // [NP][1280] q|k1|v1|k2|v2
    const float* __restrict__ canon, float rsdk,
    unsigned short* __restrict__ agg_w, unsigned short* __restrict__ agg_wb,
    int NP, int NA)
{
    int wave = threadIdx.x >> 6, lane = threadIdx.x & 63;
    int sl = lane & 31, half = lane >> 5;
    int g = blockIdx.x * 4 + wave;
    int h = sl >> 2;
    if (g < NP) {
        const unsigned short* qrow = qkv_p + (size_t)g * 1280;
        ushort8v q8 = *(const ushort8v*)(qrow + sl * 8);
        float qf[8];
        #pragma unroll
        for (int j = 0; j < 8; ++j) qf[j] = bf2f(q8[j]);
        float a[8], b[8];
        seg_agg8(offs[g], cnt[g], ssrc,
                 qkv_a + 256, 768, qkv_a + 512, 768,
                 qf, canon[h] * rsdk, sl, half, a);
        seg_agg8(offs[2 * P + g], cnt[2 * P + g], ssrc + (E0 + E1),
                 qkv_p + 768, 1280, qkv_p + 1024, 1280,
                 qf, canon[16 + h] * rsdk, sl, half, b);
        if (half == 0) {
            ushort8v o8;
            #pragma unroll
            for (int j = 0; j < 8; ++j) o8[j] = f2bf(0.5f * (a[j] + b[j]));
            *(ushort8v*)(agg_w + (size_t)g * 256 + sl * 8) = o8;
        }
    } else if (g < NP + NA) {
        int n = g - NP;
        const unsigned short* qrow = qkv_a + (size_t)n * 768;
        ushort8v q8 = *(const ushort8v*)(qrow + sl * 8);
        float qf[8];
        #pragma unroll
        for (int j = 0; j < 8; ++j) qf[j] = bf2f(q8[j]);
        float a[8];
        seg_agg8(offs[P + n], cnt[P + n], ssrc + E0,
                 qkv_p + 256, 1280, qkv_p + 512, 1280,
                 qf, canon[8 + h] * rsdk, sl, half, a);
        if (half == 0) {
            ushort8v o8;
            #pragma unroll
            for (int j = 0; j < 8; ++j) o8[j] = f2bf(a[j]);
            *(ushort8v*)(agg_wb + (size_t)n * 256 + sl * 8) = o8;
        }
    }
}

// ---------- launch ----------
extern "C" void kernel_launch(void* const* d_in, const int* in_sizes, int n_in,
                              void* d_out, int out_size, void* d_ws, size_t ws_size,
                              hipStream_t stream)
{
    const float* h_a   = (const float*)d_in[0];
    const float* h_p   = (const float*)d_in[1];
    const int* w_src   = (const int*)d_in[2];
    const int* w_dst   = (const int*)d_in[3];
    const int* wb_src  = (const int*)d_in[4];
    const int* wb_dst  = (const int*)d_in[5];
    const int* c_src   = (const int*)d_in[6];
    const int* c_dst   = (const int*)d_in[7];
    const float* Wk    = (const float*)d_in[8];
    const float* bk    = (const float*)d_in[9];
    const float* Wq    = (const float*)d_in[10];
    const float* bq    = (const float*)d_in[11];
    const float* Wv    = (const float*)d_in[12];
    const float* bv    = (const float*)d_in[13];
    const float* Wfc   = (const float*)d_in[14];
    const float* bfc   = (const float*)d_in[15];
    const float* ln_g  = (const float*)d_in[16];
    const float* ln_b  = (const float*)d_in[17];
    const float* att_w = (const float*)d_in[18];
    const float* val_w = (const float*)d_in[19];
    const float* canon = (const float*)d_in[20];
    const float* res   = (const float*)d_in[21];

    const int NA = in_sizes[0] / 256;
    const int NP = in_sizes[1] / 256;
    const int E0 = in_sizes[2];
    const int E1 = in_sizes[4];
    const int E2 = in_sizes[6];
    const int Nmax = NA > NP ? NA : NP;
    const int P = ((Nmax + 255) / 256) * 256;
    const int nbseg = P / 256;

    // workspace layout
    char* p = (char*)d_ws;
    auto alloc = [&](size_t bytes) -> char* {
        char* r = p;
        p += (bytes + 255) & ~(size_t)255;
        return r;
    };
    unsigned short* wt = (unsigned short*)alloc((size_t)10 * 65536 * 2);
    float* eff_b = (float*)alloc(6 * 256 * 4);
    float* bias_cat = (float*)alloc(2048 * 4);
    unsigned short* qkv_a = (unsigned short*)alloc((size_t)NA * 768 * 2);
    unsigned short* qkv_p = (unsigned short*)alloc((size_t)NP * 1280 * 2);
    unsigned short* agg_w  = (unsigned short*)alloc((size_t)NP * 256 * 2);
    unsigned short* agg_wb = (unsigned short*)alloc((size_t)NA * 256 * 2);
    int* cnt    = (int*)alloc((size_t)3 * P * 4);
    int* offs   = (int*)alloc((size_t)3 * P * 4);
    int* cursor = (int*)alloc((size_t)3 * P * 4);
    int* blksum = (int*)alloc((size_t)3 * nbseg * 4);
    int* ssrc   = (int*)alloc((size_t)(E0 + E1 + E2) * 4);

    // bf16 feature copies carved from d_out (dead before gemm_ln2 writes)
    unsigned short* ha_bf = (unsigned short*)d_out;
    unsigned short* hp_bf = ha_bf + (size_t)NA * 256;

    const float rsdk = 0.17677669529663687f;  // 1/sqrt(32)

    // ---- prep ----
    build_eff_t<<<1536, 256, 0, stream>>>(Wk, Wv, att_w, val_w, wt);
    build_eff_bias<<<6, 256, 0, stream>>>(bk, bv, att_w, val_w, eff_b);
    build_bias_cat<<<8, 256, 0, stream>>>(bq, eff_b, bias_cat);
    transpose_cast4<<<256, 256, 0, stream>>>(Wq, Wfc, wt);
    cast_bf16<<<(NA * 64 + 255) / 256, 256, 0, stream>>>(h_a, ha_bf, NA * 64);
    cast_bf16<<<(NP * 64 + 255) / 256, 256, 0, stream>>>(h_p, hp_bf, NP * 64);

    // ---- batched CSR build (inputs only) ----
    hipMemsetAsync(cnt, 0, (size_t)3 * P * 4, stream);
    int nb0 = (E0 + 255) / 256, nb1 = (E1 + 255) / 256, nb2 = (E2 + 255) / 256;
    k_hist3<<<nb0 + nb1 + nb2, 256, 0, stream>>>(w_dst, wb_dst, c_dst, E0, E1, E2,
                                                 nb0, nb0 + nb1, P, cnt);
    k_scan1<<<3 * nbseg, 256, 0, stream>>>(cnt, offs, blksum, 3 * P);
    k_scan2s<<<3, 512, 0, stream>>>(blksum, nbseg);
    k_scan3<<<3 * nbseg, 256, 0, stream>>>(offs, cursor, blksum, 3 * P);
    k_scatter3<<<nb0 + nb1 + nb2, 256, 0, stream>>>(w_src, w_dst, wb_src, wb_dst,
                                                    c_src, c_dst, E0, E1, E2,
                                                    nb0, nb0 + nb1, P, cursor, ssrc);

    // ---- projections ----
    int gA = (NA + 127) / 128, gP = (NP + 127) / 128;
    gemm_cat<<<dim3(gA, 6), 256, 0, stream>>>(ha_bf, wt, bias_cat, qkv_a, NA, 768);
    gemm_cat<<<dim3(gP, 10), 256, 0, stream>>>(hp_bf, wt + (size_t)768 * 256,
                                               bias_cat + 768, qkv_p, NP, 1280);

    // ---- all aggregations ----
    agg_all<<<(NP + NA + 3) / 4, 256, 0, stream>>>(cnt, offs, ssrc, P, E0, E1,
                                                   qkv_a, qkv_p, canon, rsdk,
                                                   agg_w, agg_wb, NP, NA);

    // ---- output GEMM + gate + LayerNorm (both node types, one dispatch) ----
    gemm_ln2<<<gA + gP, 512, 0, stream>>>(agg_wb, agg_w, wt + (size_t)2048 * 256,
                                          h_a, h_p, bfc, ln_g, ln_b, res,
                                          (float*)d_out, NA, NP, gA);
}